// Round 14
// baseline (540.603 us; speedup 1.0000x reference)
//
#include <hip/hip_runtime.h>
#include <hip/hip_bf16.h>
#include <math.h>

constexpr int NB = 64;     // batch
constexpr int NS = 2048;   // tokens
constexpr int ND = 1024;   // model dim
constexpr int NE = 32;     // experts
constexpr int NH = 4096;   // hidden
constexpr int NK = 8;      // top-k tokens per expert

typedef short bf16x8 __attribute__((ext_vector_type(8)));
typedef float f32x4  __attribute__((ext_vector_type(4)));

__device__ __forceinline__ unsigned short f2bf_rne(float v) {
  unsigned u = __builtin_bit_cast(unsigned, v);
  u += 0x7fffu + ((u >> 16) & 1u);
  return (unsigned short)(u >> 16);
}
__device__ __forceinline__ bf16x8 cvt8(const float (&f)[8]) {
  unsigned short h[8];
#pragma unroll
  for (int j = 0; j < 8; ++j) h[j] = f2bf_rne(f[j]);
  return *(const bf16x8*)h;
}

__device__ __forceinline__ void gload_lds16(const void* g, void* l) {
  __builtin_amdgcn_global_load_lds(
      (const __attribute__((address_space(1))) unsigned*)g,
      (__attribute__((address_space(3))) unsigned*)l, 16, 0, 0);
}

// order-preserving float->u32 (monotone), and inverse
__device__ __forceinline__ unsigned ford(float f) {
  unsigned u = __builtin_bit_cast(unsigned, f);
  return (u & 0x80000000u) ? ~u : (u | 0x80000000u);
}
__device__ __forceinline__ float finv(unsigned o) {
  unsigned u = (o & 0x80000000u) ? (o & 0x7fffffffu) : ~o;
  return __builtin_bit_cast(float, u);
}

// ---------------------------------------------------------------------------
// Kernel 1: gating GEMM, single-term bf16 MFMA — NO-LDS direct-fragment form.
// Lane l's MFMA A-fragment (row=l&15, k=(l>>4)*8..+7) is a contiguous 32B
// run of an x row: load it straight from global as 2x float4, convert in reg,
// feed MFMA. Same for gw B-fragments (L2-resident). ZERO barriers in the
// K-loop; 2-tile-deep register pipeline; each wave free-runs. Values and
// accumulation order bit-identical to the R12/R13 gate.
// LDS = 8.4KB epilogue transpose only.
// ---------------------------------------------------------------------------
__global__ __launch_bounds__(256) void k_gate_mfma(const float* __restrict__ x,
                                                   const float* __restrict__ gw,
                                                   float* __restrict__ logitsT) {
  const int b  = blockIdx.y;
  const int s0 = blockIdx.x * 64;
  const int t  = threadIdx.x;
  const int l  = t & 63;
  const int w  = t >> 6;

  __shared__ float trans[64 * 33];  // epilogue transpose

  f32x4 acc[2] = {};

  const int klane = (l >> 4) * 8;
  const float* xrow = x  + ((size_t)b * NS + s0 + w * 16 + (l & 15)) * ND + klane;
  const float* g0   = gw + (size_t)(l & 15) * ND + klane;         // experts 0-15
  const float* g1   = gw + (size_t)(16 + (l & 15)) * ND + klane;  // experts 16-31

  float aA[2][8], b0A[2][8], b1A[2][8];
  float aB[2][8], b0B[2][8], b1B[2][8];

  auto loadT = [&](int kt, float (&a)[2][8], float (&b0)[2][8], float (&b1)[2][8]) {
    const int k0 = kt * 64;
#pragma unroll
    for (int ks = 0; ks < 2; ++ks) {
      const int kk = k0 + ks * 32;
      *(float4*)&a[ks][0]  = *(const float4*)&xrow[kk];
      *(float4*)&a[ks][4]  = *(const float4*)&xrow[kk + 4];
      *(float4*)&b0[ks][0] = *(const float4*)&g0[kk];
      *(float4*)&b0[ks][4] = *(const float4*)&g0[kk + 4];
      *(float4*)&b1[ks][0] = *(const float4*)&g1[kk];
      *(float4*)&b1[ks][4] = *(const float4*)&g1[kk + 4];
    }
  };
  auto mfmaT = [&](float (&a)[2][8], float (&b0)[2][8], float (&b1)[2][8]) {
#pragma unroll
    for (int ks = 0; ks < 2; ++ks) {
      const bf16x8 av  = cvt8(a[ks]);
      const bf16x8 b0v = cvt8(b0[ks]);
      const bf16x8 b1v = cvt8(b1[ks]);
      acc[0] = __builtin_amdgcn_mfma_f32_16x16x32_bf16(av, b0v, acc[0], 0, 0, 0);
      acc[1] = __builtin_amdgcn_mfma_f32_16x16x32_bf16(av, b1v, acc[1], 0, 0, 0);
    }
  };

  loadT(0, aA, b0A, b1A);
  loadT(1, aB, b0B, b1B);
  for (int kt = 0; kt < ND / 64; kt += 2) {
    mfmaT(aA, b0A, b1A);
    if (kt + 2 < ND / 64) loadT(kt + 2, aA, b0A, b1A);
    mfmaT(aB, b0B, b1B);
    if (kt + 3 < ND / 64) loadT(kt + 3, aB, b0B, b1B);
  }

  // transpose epilogue through LDS for coalesced [e][s] stores
#pragma unroll
  for (int nf = 0; nf < 2; ++nf)
#pragma unroll
    for (int j = 0; j < 4; ++j) {
      const int sl = w * 16 + (l >> 4) * 4 + j;
      const int ec = nf * 16 + (l & 15);
      trans[sl * 33 + ec] = acc[nf][j];
    }
  __syncthreads();
  const int eo = t >> 3, sc = (t & 7) * 8;
#pragma unroll
  for (int q = 0; q < 2; ++q) {
    float4 v;
    v.x = trans[(sc + q * 4 + 0) * 33 + eo];
    v.y = trans[(sc + q * 4 + 1) * 33 + eo];
    v.z = trans[(sc + q * 4 + 2) * 33 + eo];
    v.w = trans[(sc + q * 4 + 3) * 33 + eo];
    *(float4*)&logitsT[((size_t)b * NE + eo) * NS + s0 + sc + q * 4] = v;
  }
}

// ---------------------------------------------------------------------------
// Kernel 2: topk + FUSED merge (R13, unchanged).
// ---------------------------------------------------------------------------
__global__ __launch_bounds__(256) void k_topk_merge(const float* __restrict__ logitsT,
                                                    const float* __restrict__ x,
                                                    const float* __restrict__ gw,
                                                    float* __restrict__ tval,
                                                    int* __restrict__ tidx,
                                                    unsigned short* __restrict__ A1) {
  const int be = blockIdx.x, b = be >> 5, e = be & 31;
  const float* row = logitsT + (size_t)be * NS;
  const int t = threadIdx.x, w = t >> 6, lane = t & 63;

  __shared__ unsigned long long cvp[64];
  __shared__ int    gci[16];
  __shared__ float  glc[16];
  __shared__ double wsum[4];
  __shared__ float  smax_s;
  __shared__ double ginv;
  __shared__ float  selv[8];
  __shared__ int    seli[8];

  float v[8]; int si[8];
#pragma unroll
  for (int j = 0; j < 8; ++j) {
    const int s = w * 512 + lane + j * 64;
    v[j] = row[s]; si[j] = s;
  }
#pragma unroll
  for (int i = 0; i < 7; ++i)
#pragma unroll
    for (int j = 0; j < 7 - i; ++j) {
      const bool sw = (v[j + 1] > v[j]) || (v[j + 1] == v[j] && si[j + 1] < si[j]);
      const float tv = sw ? v[j + 1] : v[j];
      const int   ti = sw ? si[j + 1] : si[j];
      v[j + 1] = sw ? v[j] : v[j + 1];  si[j + 1] = sw ? si[j] : si[j + 1];
      v[j] = tv;  si[j] = ti;
    }
  const float mxl = v[0];
  double s8 = 1.0;
#pragma unroll
  for (int j = 1; j < 8; ++j) s8 += (double)expf(v[j] - mxl);

  unsigned long long p[8];
#pragma unroll
  for (int j = 0; j < 8; ++j)
    p[j] = ((unsigned long long)ford(v[j]) << 32) | (0xFFFFFFFFu - (unsigned)si[j]);

  for (int r = 0; r < 16; ++r) {
    unsigned long long m = p[0];
#pragma unroll
    for (int off = 1; off < 64; off <<= 1) {
      const unsigned long long o = __shfl_xor(m, off);
      m = (o > m) ? o : m;
    }
    if (lane == 0) cvp[w * 16 + r] = m;
    if (p[0] == m) {
      p[0]=p[1]; p[1]=p[2]; p[2]=p[3]; p[3]=p[4]; p[4]=p[5]; p[5]=p[6]; p[6]=p[7]; p[7]=0ull;
    }
  }
  __syncthreads();

  if (w == 0) {
    const unsigned long long mine = cvp[lane];
    int rank = 0;
#pragma unroll
    for (int j = 0; j < 64; ++j) rank += (cvp[j] > mine);
    if (rank < 16) {
      gci[rank] = (int)(0xFFFFFFFFu - (unsigned)(mine & 0xFFFFFFFFu));
      if (rank == 0) smax_s = finv((unsigned)(mine >> 32));
    }
  }
  __syncthreads();

  const float mx = smax_s;
  double lsum = s8 * (double)expf(mxl - mx);
#pragma unroll
  for (int off = 32; off; off >>= 1) lsum += __shfl_xor(lsum, off);
  if (lane == 0) wsum[w] = lsum;
  __syncthreads();
  if (t == 0) ginv = 1.0 / (wsum[0] + wsum[1] + wsum[2] + wsum[3]);

  const int kb = lane * 16;
  float gwl[16];
  *(float4*)&gwl[0]  = *(const float4*)&gw[(size_t)e * ND + kb];
  *(float4*)&gwl[4]  = *(const float4*)&gw[(size_t)e * ND + kb + 4];
  *(float4*)&gwl[8]  = *(const float4*)&gw[(size_t)e * ND + kb + 8];
  *(float4*)&gwl[12] = *(const float4*)&gw[(size_t)e * ND + kb + 12];
#pragma unroll
  for (int q = 0; q < 4; ++q) {
    const int c = w * 4 + q;
    const int ciq = gci[c];
    const float* xr = x + ((size_t)b * NS + ciq) * ND + kb;
    float xv[16];
    *(float4*)&xv[0]  = *(const float4*)&xr[0];
    *(float4*)&xv[4]  = *(const float4*)&xr[4];
    *(float4*)&xv[8]  = *(const float4*)&xr[8];
    *(float4*)&xv[12] = *(const float4*)&xr[12];
    double d = 0.0;
#pragma unroll
    for (int j2 = 0; j2 < 16; ++j2) d += (double)xv[j2] * (double)gwl[j2];
#pragma unroll
    for (int off = 32; off; off >>= 1) d += __shfl_xor(d, off);
    if (lane == 0) glc[c] = (float)d;
  }
  __syncthreads();
  if (t < 16) {
    const float mylc = glc[t]; const int myci = gci[t];
    int rank = 0;
#pragma unroll
    for (int c2 = 0; c2 < 16; ++c2) {
      if (c2 == t) continue;
      rank += (glc[c2] > mylc) || (glc[c2] == mylc && gci[c2] < myci);
    }
    if (rank < 8) {
      const float pv = (float)((double)expf(mylc - mx) * ginv);
      tval[be * 8 + rank] = pv;
      tidx[be * 8 + rank] = myci;
      selv[rank] = pv;
      seli[rank] = myci;
    }
  }
  __syncthreads();

  // fused mux/merge (rank order, identical to old k_merge)
  float4 acc4 = {0.f, 0.f, 0.f, 0.f};
#pragma unroll
  for (int k = 0; k < 8; ++k) {
    const float vv = selv[k];
    const int   ss = seli[k];
    const float4 xv4 = *(const float4*)&x[((size_t)b * NS + ss) * ND + t * 4];
    acc4.x += vv * xv4.x; acc4.y += vv * xv4.y;
    acc4.z += vv * xv4.z; acc4.w += vv * xv4.w;
  }
  const int kt = t >> 4;
  const int g  = (t & 15) >> 1;
  const size_t off = ((size_t)(e * 16 + kt)) * 4096 + b * 64 + ((g ^ (b & 7)) << 3) + (t & 1) * 4;
  unsigned short h4[4] = {f2bf_rne(acc4.x), f2bf_rne(acc4.y), f2bf_rne(acc4.z), f2bf_rne(acc4.w)};
  *(ushort4*)&A1[off] = *(const ushort4*)h4;
}

// ---------------------------------------------------------------------------
// Kernels 3/4: per-expert FFN GEMM, single-bf16 MFMA, BN=64, 32KB LDS (R9).
// ---------------------------------------------------------------------------
template <int K, int N, bool GELU>
__global__ __launch_bounds__(256, 4) void k_ffn(const unsigned short* __restrict__ AT,
                                                const float* __restrict__ W,
                                                unsigned short* __restrict__ OT,
                                                float* __restrict__ Of) {
  constexpr int KT = K / 64;
  const int e  = blockIdx.y;
  const int n0 = blockIdx.x * 64;
  const int t  = threadIdx.x, l = t & 63, w = t >> 6;
  const int wr = w >> 1, wc = w & 1;

  __shared__ char smem[32768];

  const float* Wbase = W + (size_t)e * (K + 1) * N;
  f32x4 acc[2][2] = {};

  const int wn  = l;
  const int wk0 = w * 8;
  float wreg[2][8];

  auto issueW = [&](int kt) {
    const float* Wg = Wbase + (size_t)(kt * 64) * N + n0 + wn;
#pragma unroll
    for (int rn = 0; rn < 2; ++rn)
#pragma unroll
      for (int j = 0; j < 8; ++j)
        wreg[rn][j] = Wg[(size_t)(wk0 + rn * 32 + j) * N];
  };
  auto issueA = [&](int kt, int dst) {
    const unsigned short* at = AT + ((size_t)(e * KT + kt)) * 4096;
    char* Ab = smem + dst * 8192;
#pragma unroll
    for (int p = 0; p < 2; ++p)
      gload_lds16(at + p * 2048 + t * 8, Ab + p * 4096 + w * 1024);
  };
  auto commitW = [&](int dst) {
    short* Bb = (short*)(smem + 16384 + dst * 8192);
#pragma unroll
    for (int rn = 0; rn < 2; ++rn) {
      const int kr = (wk0 + rn * 32) >> 3;
      unsigned short s8[8];
#pragma unroll
      for (int j = 0; j < 8; ++j) s8[j] = f2bf_rne(wreg[rn][j]);
      *(uint4*)&Bb[wn * 64 + ((kr ^ (wn & 7)) << 3)] = *(const uint4*)s8;
    }
  };
  auto mfma_phase = [&](int cur) {
    const short* Ab = (const short*)(smem + cur * 8192);
    const short* Bb = (const short*)(smem + 16384 + cur * 8192);
#pragma unroll
    for (int ks = 0; ks < 2; ++ks) {
      const int g8 = ks * 4 + (l >> 4);
      bf16x8 a[2], bb[2];
#pragma unroll
      for (int mf = 0; mf < 2; ++mf) {
        const int m = wr * 32 + mf * 16 + (l & 15);
        a[mf] = *(const bf16x8*)&Ab[m * 64 + ((g8 ^ (m & 7)) << 3)];
      }
#pragma unroll
      for (int nf = 0; nf < 2; ++nf) {
        const int n = wc * 32 + nf * 16 + (l & 15);
        bb[nf] = *(const bf16x8*)&Bb[n * 64 + ((g8 ^ (n & 7)) << 3)];
      }
#pragma unroll
      for (int mf = 0; mf < 2; ++mf)
#pragma unroll
        for (int nf = 0; nf < 2; ++nf)
          acc[mf][nf] = __builtin_amdgcn_mfma_f32_16x16x32_bf16(a[mf], bb[nf], acc[mf][nf], 0, 0, 0);
    }
  };

  issueW(0); issueA(0, 0);
  commitW(0);
  __syncthreads();
  int cur = 0;
  for (int kt = 0; kt < KT; ++kt) {
    const bool more = (kt + 1 < KT);
    if (more) { issueW(kt + 1); issueA(kt + 1, cur ^ 1); }
    mfma_phase(cur);
    if (more) commitW(cur ^ 1);
    __syncthreads();
    cur ^= 1;
  }

  if (GELU) {
    unsigned short* transU = (unsigned short*)smem;  // [64][72]
#pragma unroll
    for (int nf = 0; nf < 2; ++nf) {
      const int c = wc * 32 + nf * 16 + (l & 15);
      const float bias = Wbase[(size_t)K * N + n0 + c];
#pragma unroll
      for (int mf = 0; mf < 2; ++mf)
#pragma unroll
        for (int j = 0; j < 4; ++j) {
          const int m = wr * 32 + mf * 16 + (l >> 4) * 4 + j;
          float vv = acc[mf][nf][j] + bias;
          vv = 0.5f * vv * (1.0f + erff(vv * 0.70710678118654752440f));
          transU[m * 72 + c] = f2bf_rne(vv);
        }
    }
    __syncthreads();
    const int m  = t >> 2;
    const int c0 = (t & 3) * 16;
    const size_t tb = ((size_t)(e * (N / 64) + blockIdx.x)) * 4096;
    uint4 v0 = *(const uint4*)&transU[m * 72 + c0];
    uint4 v1 = *(const uint4*)&transU[m * 72 + c0 + 8];
    const int g0 = c0 >> 3;
    *(uint4*)&OT[tb + m * 64 + ((g0 ^ (m & 7)) << 3)]       = v0;
    *(uint4*)&OT[tb + m * 64 + (((g0 + 1) ^ (m & 7)) << 3)] = v1;
  } else {
    float* transF = (float*)smem;  // [64][68]
#pragma unroll
    for (int nf = 0; nf < 2; ++nf) {
      const int c = wc * 32 + nf * 16 + (l & 15);
      const float bias = Wbase[(size_t)K * N + n0 + c];
#pragma unroll
      for (int mf = 0; mf < 2; ++mf)
#pragma unroll
        for (int j = 0; j < 4; ++j) {
          const int m = wr * 32 + mf * 16 + (l >> 4) * 4 + j;
          transF[m * 68 + c] = acc[mf][nf][j] + bias;
        }
    }
    __syncthreads();
    const int m  = t >> 2;
    const int c0 = (t & 3) * 16;
    float* og = Of + ((size_t)m * NE + e) * ND + n0 + c0;
    *(float4*)&og[0]  = *(const float4*)&transF[m * 68 + c0];
    *(float4*)&og[4]  = *(const float4*)&transF[m * 68 + c0 + 4];
    *(float4*)&og[8]  = *(const float4*)&transF[m * 68 + c0 + 8];
    *(float4*)&og[12] = *(const float4*)&transF[m * 68 + c0 + 12];
  }
}

// ---------------------------------------------------------------------------
// Kernel 5: demux/scatter, 8 tokens per block (R9 form).
// ---------------------------------------------------------------------------
__global__ __launch_bounds__(256) void k_scatter(const float* __restrict__ Obuf,
                                                 const float* __restrict__ tval,
                                                 const int* __restrict__ tidx,
                                                 float* __restrict__ out) {
  const int s0 = blockIdx.x * 8;
  const int b  = blockIdx.y;
  const int t  = threadIdx.x;
  const int w  = t >> 6;
  __shared__ unsigned long long masks[8][4];

  const int myIdx = tidx[b * 256 + t];
#pragma unroll
  for (int j = 0; j < 8; ++j) {
    unsigned long long m = __ballot(myIdx == s0 + j);
    if ((t & 63) == 0) masks[j][w] = m;
  }
  __syncthreads();

#pragma unroll
  for (int j = 0; j < 8; ++j) {
    float4 acc = {0.f, 0.f, 0.f, 0.f};
#pragma unroll
    for (int q = 0; q < 4; ++q) {
      unsigned long long mm = masks[j][q];
      while (mm) {
        int bit = __ffsll(mm) - 1;
        mm &= mm - 1;
        int r = q * 64 + bit;
        float v = tval[b * 256 + r];
        const float4 ov = *(const float4*)&Obuf[((size_t)b * NE + (r >> 3)) * ND + t * 4];
        acc.x += v * ov.x; acc.y += v * ov.y; acc.z += v * ov.z; acc.w += v * ov.w;
      }
    }
    *(float4*)&out[((size_t)b * NS + s0 + j) * ND + t * 4] = acc;
  }
}

// ---------------------------------------------------------------------------
extern "C" void kernel_launch(void* const* d_in, const int* in_sizes, int n_in,
                              void* d_out, int out_size, void* d_ws, size_t ws_size,
                              hipStream_t stream) {
  const float* x  = (const float*)d_in[0];
  const float* gw = (const float*)d_in[1];
  const float* w1 = (const float*)d_in[3];
  const float* w2 = (const float*)d_in[4];
  float* out = (float*)d_out;

  char* ws = (char*)d_ws;
  float* logitsT     = (float*)ws;                         // 16,777,216 B
  float* tval        = (float*)(ws + 16777216);            //     65,536 B
  int*   tidx        = (int*)  (ws + 16842752);            //     65,536 B
  unsigned short* A1 = (unsigned short*)(ws + 16908288);   //  4,194,304 B (bf16 tiles)
  unsigned short* Hb = (unsigned short*)(ws + 21102592);   // 16,777,216 B (bf16 tiles)
  float* Obuf        = (float*)(ws + 37879808);            //  8,388,608 B

  k_gate_mfma<<<dim3(NS / 64, NB), 256, 0, stream>>>(x, gw, logitsT);
  k_topk_merge<<<NB * NE, 256, 0, stream>>>(logitsT, x, gw, tval, tidx, A1);
  k_ffn<ND, NH, true ><<<dim3(NH / 64, NE), 256, 0, stream>>>(A1, w1, Hb, nullptr);
  k_ffn<NH, ND, false><<<dim3(ND / 64, NE), 256, 0, stream>>>(Hb, w2, nullptr, Obuf);
  k_scatter<<<dim3(NS / 8, NB), 256, 0, stream>>>(Obuf, tval, tidx, out);
}

// Round 15
// 524.410 us; speedup vs baseline: 1.0309x; 1.0309x over previous
//
#include <hip/hip_runtime.h>
#include <hip/hip_bf16.h>
#include <math.h>

constexpr int NB = 64;     // batch
constexpr int NS = 2048;   // tokens
constexpr int ND = 1024;   // model dim
constexpr int NE = 32;     // experts
constexpr int NH = 4096;   // hidden
constexpr int NK = 8;      // top-k tokens per expert

typedef short bf16x8 __attribute__((ext_vector_type(8)));
typedef float f32x4  __attribute__((ext_vector_type(4)));

__device__ __forceinline__ unsigned short f2bf_rne(float v) {
  unsigned u = __builtin_bit_cast(unsigned, v);
  u += 0x7fffu + ((u >> 16) & 1u);
  return (unsigned short)(u >> 16);
}

__device__ __forceinline__ void gload_lds16(const void* g, void* l) {
  __builtin_amdgcn_global_load_lds(
      (const __attribute__((address_space(1))) unsigned*)g,
      (__attribute__((address_space(3))) unsigned*)l, 16, 0, 0);
}

// order-preserving float->u32 (monotone), and inverse
__device__ __forceinline__ unsigned ford(float f) {
  unsigned u = __builtin_bit_cast(unsigned, f);
  return (u & 0x80000000u) ? ~u : (u | 0x80000000u);
}
__device__ __forceinline__ float finv(unsigned o) {
  unsigned u = (o & 0x80000000u) ? (o & 0x7fffffffu) : ~o;
  return __builtin_bit_cast(float, u);
}

// ---------------------------------------------------------------------------
// Kernel 1: gating GEMM, single-term bf16 MFMA, 64-token tiles, 24KB LDS.
// GRID-STRIDE: 1024 blocks (4/CU, all co-resident — no dispatch tail), each
// processes two 64-token tiles. Per-tile body = R12/R13 T4 pipeline (two
// register sets, raw s_barrier with lgkmcnt-only, x2-unrolled K-loop).
// ---------------------------------------------------------------------------
__global__ __launch_bounds__(256) void k_gate_mfma(const float* __restrict__ x,
                                                   const float* __restrict__ gw,
                                                   float* __restrict__ logitsT) {
  const int b  = blockIdx.y;
  const int t  = threadIdx.x;
  const int l  = t & 63;
  const int w  = t >> 6;

  __shared__ char smem[24576];
  float* trans = (float*)smem;

  const int ar  = t >> 2;
  const int ac4 = (t & 3) * 16;
  const int ge  = t >> 3;
  const int gk  = (t & 7) * 8;

  for (int half = 0; half < 2; ++half) {
    const int s0 = (blockIdx.x + half * 16) * 64;

    f32x4 acc[2] = {};
    float xA[4][4], xB[4][4], wA[8], wB[8];

    auto issue = [&](int kt, float (&xreg)[4][4], float (&wreg)[8]) {
      const int k0 = kt * 64;
      const float* xr = &x[((size_t)b * NS + s0 + ar) * ND + k0 + ac4];
#pragma unroll
      for (int j = 0; j < 4; ++j) *(float4*)xreg[j] = *(const float4*)&xr[j * 4];
      *(float4*)&wreg[0] = *(const float4*)&gw[(size_t)ge * ND + k0 + gk];
      *(float4*)&wreg[4] = *(const float4*)&gw[(size_t)ge * ND + k0 + gk + 4];
    };
    auto commit = [&](int dst, float (&xreg)[4][4], float (&wreg)[8]) {
      short* Ah = (short*)(smem + dst * 8192);
      short* Bh = (short*)(smem + 16384 + dst * 4096);
#pragma unroll
      for (int j = 0; j < 4; ++j) {
        unsigned short h[4];
#pragma unroll
        for (int q = 0; q < 4; ++q) h[q] = f2bf_rne(xreg[j][q]);
        const int col = ac4 + j * 4;
        *(ushort4*)&Ah[ar * 64 + (col ^ ((ar & 7) * 8))] = *(const ushort4*)h;
      }
      unsigned short h8[8];
#pragma unroll
      for (int j = 0; j < 8; ++j) h8[j] = f2bf_rne(wreg[j]);
      *(uint4*)&Bh[ge * 64 + (gk ^ ((ge & 7) * 8))] = *(const uint4*)h8;
    };
    auto mfma_phase = [&](int cur) {
      const short* Ah = (const short*)(smem + cur * 8192);
      const short* Bh = (const short*)(smem + 16384 + cur * 4096);
#pragma unroll
      for (int ks = 0; ks < 2; ++ks) {
        const int koff = ks * 32 + (l >> 4) * 8;
        const int rl = w * 16 + (l & 15);
        bf16x8 a = *(const bf16x8*)&Ah[rl * 64 + (koff ^ ((rl & 7) * 8))];
#pragma unroll
        for (int nf = 0; nf < 2; ++nf) {
          const int n = nf * 16 + (l & 15);
          bf16x8 bb = *(const bf16x8*)&Bh[n * 64 + (koff ^ ((n & 7) * 8))];
          acc[nf] = __builtin_amdgcn_mfma_f32_16x16x32_bf16(a, bb, acc[nf], 0, 0, 0);
        }
      }
    };
    auto bar = [&]() {
      asm volatile("s_waitcnt lgkmcnt(0)" ::: "memory");
      __builtin_amdgcn_s_barrier();
      __builtin_amdgcn_sched_barrier(0);
    };

    issue(0, xA, wA);
    issue(1, xB, wB);
    commit(0, xA, wA);
    bar();

    for (int kt = 0; kt < ND / 64; kt += 2) {
      if (kt + 2 < ND / 64) issue(kt + 2, xA, wA);
      commit(1, xB, wB);
      mfma_phase(0);
      bar();
      if (kt + 3 < ND / 64) issue(kt + 3, xB, wB);
      if (kt + 2 < ND / 64) commit(0, xA, wA);
      mfma_phase(1);
      bar();
    }

    // transpose epilogue through LDS for coalesced [e][s] stores
#pragma unroll
    for (int nf = 0; nf < 2; ++nf)
#pragma unroll
      for (int j = 0; j < 4; ++j) {
        const int sl = w * 16 + (l >> 4) * 4 + j;
        const int ec = nf * 16 + (l & 15);
        trans[sl * 33 + ec] = acc[nf][j];
      }
    __syncthreads();
    const int eo = t >> 3, sc = (t & 7) * 8;
#pragma unroll
    for (int q = 0; q < 2; ++q) {
      float4 v;
      v.x = trans[(sc + q * 4 + 0) * 33 + eo];
      v.y = trans[(sc + q * 4 + 1) * 33 + eo];
      v.z = trans[(sc + q * 4 + 2) * 33 + eo];
      v.w = trans[(sc + q * 4 + 3) * 33 + eo];
      *(float4*)&logitsT[((size_t)b * NE + eo) * NS + s0 + sc + q * 4] = v;
    }
    __syncthreads();  // trans/A-buffer reuse safe before next half
  }
}

// ---------------------------------------------------------------------------
// Kernel 2: topk + FUSED merge (R13, unchanged).
// ---------------------------------------------------------------------------
__global__ __launch_bounds__(256) void k_topk_merge(const float* __restrict__ logitsT,
                                                    const float* __restrict__ x,
                                                    const float* __restrict__ gw,
                                                    float* __restrict__ tval,
                                                    int* __restrict__ tidx,
                                                    unsigned short* __restrict__ A1) {
  const int be = blockIdx.x, b = be >> 5, e = be & 31;
  const float* row = logitsT + (size_t)be * NS;
  const int t = threadIdx.x, w = t >> 6, lane = t & 63;

  __shared__ unsigned long long cvp[64];
  __shared__ int    gci[16];
  __shared__ float  glc[16];
  __shared__ double wsum[4];
  __shared__ float  smax_s;
  __shared__ double ginv;
  __shared__ float  selv[8];
  __shared__ int    seli[8];

  float v[8]; int si[8];
#pragma unroll
  for (int j = 0; j < 8; ++j) {
    const int s = w * 512 + lane + j * 64;
    v[j] = row[s]; si[j] = s;
  }
#pragma unroll
  for (int i = 0; i < 7; ++i)
#pragma unroll
    for (int j = 0; j < 7 - i; ++j) {
      const bool sw = (v[j + 1] > v[j]) || (v[j + 1] == v[j] && si[j + 1] < si[j]);
      const float tv = sw ? v[j + 1] : v[j];
      const int   ti = sw ? si[j + 1] : si[j];
      v[j + 1] = sw ? v[j] : v[j + 1];  si[j + 1] = sw ? si[j] : si[j + 1];
      v[j] = tv;  si[j] = ti;
    }
  const float mxl = v[0];
  double s8 = 1.0;
#pragma unroll
  for (int j = 1; j < 8; ++j) s8 += (double)expf(v[j] - mxl);

  unsigned long long p[8];
#pragma unroll
  for (int j = 0; j < 8; ++j)
    p[j] = ((unsigned long long)ford(v[j]) << 32) | (0xFFFFFFFFu - (unsigned)si[j]);

  for (int r = 0; r < 16; ++r) {
    unsigned long long m = p[0];
#pragma unroll
    for (int off = 1; off < 64; off <<= 1) {
      const unsigned long long o = __shfl_xor(m, off);
      m = (o > m) ? o : m;
    }
    if (lane == 0) cvp[w * 16 + r] = m;
    if (p[0] == m) {
      p[0]=p[1]; p[1]=p[2]; p[2]=p[3]; p[3]=p[4]; p[4]=p[5]; p[5]=p[6]; p[6]=p[7]; p[7]=0ull;
    }
  }
  __syncthreads();

  if (w == 0) {
    const unsigned long long mine = cvp[lane];
    int rank = 0;
#pragma unroll
    for (int j = 0; j < 64; ++j) rank += (cvp[j] > mine);
    if (rank < 16) {
      gci[rank] = (int)(0xFFFFFFFFu - (unsigned)(mine & 0xFFFFFFFFu));
      if (rank == 0) smax_s = finv((unsigned)(mine >> 32));
    }
  }
  __syncthreads();

  const float mx = smax_s;
  double lsum = s8 * (double)expf(mxl - mx);
#pragma unroll
  for (int off = 32; off; off >>= 1) lsum += __shfl_xor(lsum, off);
  if (lane == 0) wsum[w] = lsum;
  __syncthreads();
  if (t == 0) ginv = 1.0 / (wsum[0] + wsum[1] + wsum[2] + wsum[3]);

  const int kb = lane * 16;
  float gwl[16];
  *(float4*)&gwl[0]  = *(const float4*)&gw[(size_t)e * ND + kb];
  *(float4*)&gwl[4]  = *(const float4*)&gw[(size_t)e * ND + kb + 4];
  *(float4*)&gwl[8]  = *(const float4*)&gw[(size_t)e * ND + kb + 8];
  *(float4*)&gwl[12] = *(const float4*)&gw[(size_t)e * ND + kb + 12];
#pragma unroll
  for (int q = 0; q < 4; ++q) {
    const int c = w * 4 + q;
    const int ciq = gci[c];
    const float* xr = x + ((size_t)b * NS + ciq) * ND + kb;
    float xv[16];
    *(float4*)&xv[0]  = *(const float4*)&xr[0];
    *(float4*)&xv[4]  = *(const float4*)&xr[4];
    *(float4*)&xv[8]  = *(const float4*)&xr[8];
    *(float4*)&xv[12] = *(const float4*)&xr[12];
    double d = 0.0;
#pragma unroll
    for (int j2 = 0; j2 < 16; ++j2) d += (double)xv[j2] * (double)gwl[j2];
#pragma unroll
    for (int off = 32; off; off >>= 1) d += __shfl_xor(d, off);
    if (lane == 0) glc[c] = (float)d;
  }
  __syncthreads();
  if (t < 16) {
    const float mylc = glc[t]; const int myci = gci[t];
    int rank = 0;
#pragma unroll
    for (int c2 = 0; c2 < 16; ++c2) {
      if (c2 == t) continue;
      rank += (glc[c2] > mylc) || (glc[c2] == mylc && gci[c2] < myci);
    }
    if (rank < 8) {
      const float pv = (float)((double)expf(mylc - mx) * ginv);
      tval[be * 8 + rank] = pv;
      tidx[be * 8 + rank] = myci;
      selv[rank] = pv;
      seli[rank] = myci;
    }
  }
  __syncthreads();

  // fused mux/merge (rank order, identical to old k_merge)
  float4 acc4 = {0.f, 0.f, 0.f, 0.f};
#pragma unroll
  for (int k = 0; k < 8; ++k) {
    const float vv = selv[k];
    const int   ss = seli[k];
    const float4 xv4 = *(const float4*)&x[((size_t)b * NS + ss) * ND + t * 4];
    acc4.x += vv * xv4.x; acc4.y += vv * xv4.y;
    acc4.z += vv * xv4.z; acc4.w += vv * xv4.w;
  }
  const int kt = t >> 4;
  const int g  = (t & 15) >> 1;
  const size_t off = ((size_t)(e * 16 + kt)) * 4096 + b * 64 + ((g ^ (b & 7)) << 3) + (t & 1) * 4;
  unsigned short h4[4] = {f2bf_rne(acc4.x), f2bf_rne(acc4.y), f2bf_rne(acc4.z), f2bf_rne(acc4.w)};
  *(ushort4*)&A1[off] = *(const ushort4*)h4;
}

// ---------------------------------------------------------------------------
// Kernels 3/4: per-expert FFN GEMM, single-bf16 MFMA, BN=64, 32KB LDS (R9).
// ---------------------------------------------------------------------------
template <int K, int N, bool GELU>
__global__ __launch_bounds__(256, 4) void k_ffn(const unsigned short* __restrict__ AT,
                                                const float* __restrict__ W,
                                                unsigned short* __restrict__ OT,
                                                float* __restrict__ Of) {
  constexpr int KT = K / 64;
  const int e  = blockIdx.y;
  const int n0 = blockIdx.x * 64;
  const int t  = threadIdx.x, l = t & 63, w = t >> 6;
  const int wr = w >> 1, wc = w & 1;

  __shared__ char smem[32768];

  const float* Wbase = W + (size_t)e * (K + 1) * N;
  f32x4 acc[2][2] = {};

  const int wn  = l;
  const int wk0 = w * 8;
  float wreg[2][8];

  auto issueW = [&](int kt) {
    const float* Wg = Wbase + (size_t)(kt * 64) * N + n0 + wn;
#pragma unroll
    for (int rn = 0; rn < 2; ++rn)
#pragma unroll
      for (int j = 0; j < 8; ++j)
        wreg[rn][j] = Wg[(size_t)(wk0 + rn * 32 + j) * N];
  };
  auto issueA = [&](int kt, int dst) {
    const unsigned short* at = AT + ((size_t)(e * KT + kt)) * 4096;
    char* Ab = smem + dst * 8192;
#pragma unroll
    for (int p = 0; p < 2; ++p)
      gload_lds16(at + p * 2048 + t * 8, Ab + p * 4096 + w * 1024);
  };
  auto commitW = [&](int dst) {
    short* Bb = (short*)(smem + 16384 + dst * 8192);
#pragma unroll
    for (int rn = 0; rn < 2; ++rn) {
      const int kr = (wk0 + rn * 32) >> 3;
      unsigned short s8[8];
#pragma unroll
      for (int j = 0; j < 8; ++j) s8[j] = f2bf_rne(wreg[rn][j]);
      *(uint4*)&Bb[wn * 64 + ((kr ^ (wn & 7)) << 3)] = *(const uint4*)s8;
    }
  };
  auto mfma_phase = [&](int cur) {
    const short* Ab = (const short*)(smem + cur * 8192);
    const short* Bb = (const short*)(smem + 16384 + cur * 8192);
#pragma unroll
    for (int ks = 0; ks < 2; ++ks) {
      const int g8 = ks * 4 + (l >> 4);
      bf16x8 a[2], bb[2];
#pragma unroll
      for (int mf = 0; mf < 2; ++mf) {
        const int m = wr * 32 + mf * 16 + (l & 15);
        a[mf] = *(const bf16x8*)&Ab[m * 64 + ((g8 ^ (m & 7)) << 3)];
      }
#pragma unroll
      for (int nf = 0; nf < 2; ++nf) {
        const int n = wc * 32 + nf * 16 + (l & 15);
        bb[nf] = *(const bf16x8*)&Bb[n * 64 + ((g8 ^ (n & 7)) << 3)];
      }
#pragma unroll
      for (int mf = 0; mf < 2; ++mf)
#pragma unroll
        for (int nf = 0; nf < 2; ++nf)
          acc[mf][nf] = __builtin_amdgcn_mfma_f32_16x16x32_bf16(a[mf], bb[nf], acc[mf][nf], 0, 0, 0);
    }
  };

  issueW(0); issueA(0, 0);
  commitW(0);
  __syncthreads();
  int cur = 0;
  for (int kt = 0; kt < KT; ++kt) {
    const bool more = (kt + 1 < KT);
    if (more) { issueW(kt + 1); issueA(kt + 1, cur ^ 1); }
    mfma_phase(cur);
    if (more) commitW(cur ^ 1);
    __syncthreads();
    cur ^= 1;
  }

  if (GELU) {
    unsigned short* transU = (unsigned short*)smem;  // [64][72]
#pragma unroll
    for (int nf = 0; nf < 2; ++nf) {
      const int c = wc * 32 + nf * 16 + (l & 15);
      const float bias = Wbase[(size_t)K * N + n0 + c];
#pragma unroll
      for (int mf = 0; mf < 2; ++mf)
#pragma unroll
        for (int j = 0; j < 4; ++j) {
          const int m = wr * 32 + mf * 16 + (l >> 4) * 4 + j;
          float vv = acc[mf][nf][j] + bias;
          vv = 0.5f * vv * (1.0f + erff(vv * 0.70710678118654752440f));
          transU[m * 72 + c] = f2bf_rne(vv);
        }
    }
    __syncthreads();
    const int m  = t >> 2;
    const int c0 = (t & 3) * 16;
    const size_t tb = ((size_t)(e * (N / 64) + blockIdx.x)) * 4096;
    uint4 v0 = *(const uint4*)&transU[m * 72 + c0];
    uint4 v1 = *(const uint4*)&transU[m * 72 + c0 + 8];
    const int g0 = c0 >> 3;
    *(uint4*)&OT[tb + m * 64 + ((g0 ^ (m & 7)) << 3)]       = v0;
    *(uint4*)&OT[tb + m * 64 + (((g0 + 1) ^ (m & 7)) << 3)] = v1;
  } else {
    float* transF = (float*)smem;  // [64][68]
#pragma unroll
    for (int nf = 0; nf < 2; ++nf) {
      const int c = wc * 32 + nf * 16 + (l & 15);
      const float bias = Wbase[(size_t)K * N + n0 + c];
#pragma unroll
      for (int mf = 0; mf < 2; ++mf)
#pragma unroll
        for (int j = 0; j < 4; ++j) {
          const int m = wr * 32 + mf * 16 + (l >> 4) * 4 + j;
          transF[m * 68 + c] = acc[mf][nf][j] + bias;
        }
    }
    __syncthreads();
    const int m  = t >> 2;
    const int c0 = (t & 3) * 16;
    float* og = Of + ((size_t)m * NE + e) * ND + n0 + c0;
    *(float4*)&og[0]  = *(const float4*)&transF[m * 68 + c0];
    *(float4*)&og[4]  = *(const float4*)&transF[m * 68 + c0 + 4];
    *(float4*)&og[8]  = *(const float4*)&transF[m * 68 + c0 + 8];
    *(float4*)&og[12] = *(const float4*)&transF[m * 68 + c0 + 12];
  }
}

// ---------------------------------------------------------------------------
// Kernel 5: demux/scatter, 8 tokens per block (R9 form).
// ---------------------------------------------------------------------------
__global__ __launch_bounds__(256) void k_scatter(const float* __restrict__ Obuf,
                                                 const float* __restrict__ tval,
                                                 const int* __restrict__ tidx,
                                                 float* __restrict__ out) {
  const int s0 = blockIdx.x * 8;
  const int b  = blockIdx.y;
  const int t  = threadIdx.x;
  const int w  = t >> 6;
  __shared__ unsigned long long masks[8][4];

  const int myIdx = tidx[b * 256 + t];
#pragma unroll
  for (int j = 0; j < 8; ++j) {
    unsigned long long m = __ballot(myIdx == s0 + j);
    if ((t & 63) == 0) masks[j][w] = m;
  }
  __syncthreads();

#pragma unroll
  for (int j = 0; j < 8; ++j) {
    float4 acc = {0.f, 0.f, 0.f, 0.f};
#pragma unroll
    for (int q = 0; q < 4; ++q) {
      unsigned long long mm = masks[j][q];
      while (mm) {
        int bit = __ffsll(mm) - 1;
        mm &= mm - 1;
        int r = q * 64 + bit;
        float v = tval[b * 256 + r];
        const float4 ov = *(const float4*)&Obuf[((size_t)b * NE + (r >> 3)) * ND + t * 4];
        acc.x += v * ov.x; acc.y += v * ov.y; acc.z += v * ov.z; acc.w += v * ov.w;
      }
    }
    *(float4*)&out[((size_t)b * NS + s0 + j) * ND + t * 4] = acc;
  }
}

// ---------------------------------------------------------------------------
extern "C" void kernel_launch(void* const* d_in, const int* in_sizes, int n_in,
                              void* d_out, int out_size, void* d_ws, size_t ws_size,
                              hipStream_t stream) {
  const float* x  = (const float*)d_in[0];
  const float* gw = (const float*)d_in[1];
  const float* w1 = (const float*)d_in[3];
  const float* w2 = (const float*)d_in[4];
  float* out = (float*)d_out;

  char* ws = (char*)d_ws;
  float* logitsT     = (float*)ws;                         // 16,777,216 B
  float* tval        = (float*)(ws + 16777216);            //     65,536 B
  int*   tidx        = (int*)  (ws + 16842752);            //     65,536 B
  unsigned short* A1 = (unsigned short*)(ws + 16908288);   //  4,194,304 B (bf16 tiles)
  unsigned short* Hb = (unsigned short*)(ws + 21102592);   // 16,777,216 B (bf16 tiles)
  float* Obuf        = (float*)(ws + 37879808);            //  8,388,608 B

  k_gate_mfma<<<dim3(16, NB), 256, 0, stream>>>(x, gw, logitsT);
  k_topk_merge<<<NB * NE, 256, 0, stream>>>(logitsT, x, gw, tval, tidx, A1);
  k_ffn<ND, NH, true ><<<dim3(NH / 64, NE), 256, 0, stream>>>(A1, w1, Hb, nullptr);
  k_ffn<NH, ND, false><<<dim3(ND / 64, NE), 256, 0, stream>>>(Hb, w2, nullptr, Obuf);
  k_scatter<<<dim3(NS / 8, NB), 256, 0, stream>>>(Obuf, tval, tidx, out);
}

// Round 16
// 514.455 us; speedup vs baseline: 1.0508x; 1.0194x over previous
//
#include <hip/hip_runtime.h>
#include <hip/hip_bf16.h>
#include <math.h>

constexpr int NB = 64;     // batch
constexpr int NS = 2048;   // tokens
constexpr int ND = 1024;   // model dim
constexpr int NE = 32;     // experts
constexpr int NH = 4096;   // hidden
constexpr int NK = 8;      // top-k tokens per expert

typedef short bf16x8 __attribute__((ext_vector_type(8)));
typedef float f32x4  __attribute__((ext_vector_type(4)));

__device__ __forceinline__ unsigned short f2bf_rne(float v) {
  unsigned u = __builtin_bit_cast(unsigned, v);
  u += 0x7fffu + ((u >> 16) & 1u);
  return (unsigned short)(u >> 16);
}

__device__ __forceinline__ void gload_lds16(const void* g, void* l) {
  __builtin_amdgcn_global_load_lds(
      (const __attribute__((address_space(1))) unsigned*)g,
      (__attribute__((address_space(3))) unsigned*)l, 16, 0, 0);
}

// order-preserving float->u32 (monotone), and inverse
__device__ __forceinline__ unsigned ford(float f) {
  unsigned u = __builtin_bit_cast(unsigned, f);
  return (u & 0x80000000u) ? ~u : (u | 0x80000000u);
}
__device__ __forceinline__ float finv(unsigned o) {
  unsigned u = (o & 0x80000000u) ? (o & 0x7fffffffu) : ~o;
  return __builtin_bit_cast(float, u);
}

// ---------------------------------------------------------------------------
// Kernel 1: gating GEMM, single-term bf16 MFMA. 512 threads (8 waves),
// 128-token tiles, LDS 40KB (A dbuf 2x16KB + B dbuf 2x4KB) -> 4 blocks/CU x
// 8 waves = 32 waves/CU (HW max), grid 16x64 = 1024 = exactly 4/CU, no tail.
// T4 pipeline: two register sets, raw s_barrier with lgkmcnt-only,
// x2-unrolled K-loop. Arithmetic identical to R13.
// ---------------------------------------------------------------------------
__global__ __launch_bounds__(512) void k_gate_mfma(const float* __restrict__ x,
                                                   const float* __restrict__ gw,
                                                   float* __restrict__ logitsT) {
  const int b  = blockIdx.y;
  const int s0 = blockIdx.x * 128;
  const int t  = threadIdx.x;
  const int l  = t & 63;
  const int w  = t >> 6;

  __shared__ char smem[40960];
  // A buf d: smem + d*16384 ([128][64] swz bf16); B buf d: smem + 32768 + d*4096
  float* trans = (float*)smem;  // [128][33] epilogue (reuses A bufs)

  f32x4 acc[2] = {};

  const int ar  = t >> 2;          // A staging: row 0..127 (4 thr/row)
  const int ac4 = (t & 3) * 16;    // A staging: col base (4 float4)
  const int ge  = t >> 4;          // B staging: expert row 0..31 (16 thr/row)
  const int gk  = (t & 15) * 4;    // B staging: col base (1 float4)

  float xA[4][4], xB[4][4], wA[4], wB[4];

  auto issue = [&](int kt, float (&xreg)[4][4], float (&wreg)[4]) {
    const int k0 = kt * 64;
    const float* xr = &x[((size_t)b * NS + s0 + ar) * ND + k0 + ac4];
#pragma unroll
    for (int j = 0; j < 4; ++j) *(float4*)xreg[j] = *(const float4*)&xr[j * 4];
    *(float4*)&wreg[0] = *(const float4*)&gw[(size_t)ge * ND + k0 + gk];
  };
  auto commit = [&](int dst, float (&xreg)[4][4], float (&wreg)[4]) {
    short* Ah = (short*)(smem + dst * 16384);
    short* Bh = (short*)(smem + 32768 + dst * 4096);
#pragma unroll
    for (int j = 0; j < 4; ++j) {
      unsigned short h[4];
#pragma unroll
      for (int q = 0; q < 4; ++q) h[q] = f2bf_rne(xreg[j][q]);
      const int col = ac4 + j * 4;
      *(ushort4*)&Ah[ar * 64 + (col ^ ((ar & 7) * 8))] = *(const ushort4*)h;
    }
    unsigned short h4[4];
#pragma unroll
    for (int j = 0; j < 4; ++j) h4[j] = f2bf_rne(wreg[j]);
    // XOR with multiple of 8 leaves low 3 bits intact -> valid for 4-granule
    *(ushort4*)&Bh[ge * 64 + (gk ^ ((ge & 7) * 8))] = *(const ushort4*)h4;
  };
  auto mfma_phase = [&](int cur) {
    const short* Ah = (const short*)(smem + cur * 16384);
    const short* Bh = (const short*)(smem + 32768 + cur * 4096);
#pragma unroll
    for (int ks = 0; ks < 2; ++ks) {
      const int koff = ks * 32 + (l >> 4) * 8;
      const int rl = w * 16 + (l & 15);
      bf16x8 a = *(const bf16x8*)&Ah[rl * 64 + (koff ^ ((rl & 7) * 8))];
#pragma unroll
      for (int nf = 0; nf < 2; ++nf) {
        const int n = nf * 16 + (l & 15);
        bf16x8 bb = *(const bf16x8*)&Bh[n * 64 + (koff ^ ((n & 7) * 8))];
        acc[nf] = __builtin_amdgcn_mfma_f32_16x16x32_bf16(a, bb, acc[nf], 0, 0, 0);
      }
    }
  };
  auto bar = [&]() {
    asm volatile("s_waitcnt lgkmcnt(0)" ::: "memory");
    __builtin_amdgcn_s_barrier();
    __builtin_amdgcn_sched_barrier(0);
  };

  issue(0, xA, wA);
  issue(1, xB, wB);
  commit(0, xA, wA);
  bar();

  for (int kt = 0; kt < ND / 64; kt += 2) {
    if (kt + 2 < ND / 64) issue(kt + 2, xA, wA);
    commit(1, xB, wB);
    mfma_phase(0);
    bar();
    if (kt + 3 < ND / 64) issue(kt + 3, xB, wB);
    if (kt + 2 < ND / 64) commit(0, xA, wA);
    mfma_phase(1);
    bar();
  }

  // transpose epilogue through LDS for coalesced [e][s] stores
#pragma unroll
  for (int nf = 0; nf < 2; ++nf)
#pragma unroll
    for (int j = 0; j < 4; ++j) {
      const int sl = w * 16 + (l >> 4) * 4 + j;
      const int ec = nf * 16 + (l & 15);
      trans[sl * 33 + ec] = acc[nf][j];
    }
  __syncthreads();
  const int eo = t >> 4, sc = (t & 15) * 8;
#pragma unroll
  for (int q = 0; q < 2; ++q) {
    float4 v;
    v.x = trans[(sc + q * 4 + 0) * 33 + eo];
    v.y = trans[(sc + q * 4 + 1) * 33 + eo];
    v.z = trans[(sc + q * 4 + 2) * 33 + eo];
    v.w = trans[(sc + q * 4 + 3) * 33 + eo];
    *(float4*)&logitsT[((size_t)b * NE + eo) * NS + s0 + sc + q * 4] = v;
  }
}

// ---------------------------------------------------------------------------
// Kernel 2: topk + FUSED merge (R13, unchanged).
// ---------------------------------------------------------------------------
__global__ __launch_bounds__(256) void k_topk_merge(const float* __restrict__ logitsT,
                                                    const float* __restrict__ x,
                                                    const float* __restrict__ gw,
                                                    float* __restrict__ tval,
                                                    int* __restrict__ tidx,
                                                    unsigned short* __restrict__ A1) {
  const int be = blockIdx.x, b = be >> 5, e = be & 31;
  const float* row = logitsT + (size_t)be * NS;
  const int t = threadIdx.x, w = t >> 6, lane = t & 63;

  __shared__ unsigned long long cvp[64];
  __shared__ int    gci[16];
  __shared__ float  glc[16];
  __shared__ double wsum[4];
  __shared__ float  smax_s;
  __shared__ double ginv;
  __shared__ float  selv[8];
  __shared__ int    seli[8];

  float v[8]; int si[8];
#pragma unroll
  for (int j = 0; j < 8; ++j) {
    const int s = w * 512 + lane + j * 64;
    v[j] = row[s]; si[j] = s;
  }
#pragma unroll
  for (int i = 0; i < 7; ++i)
#pragma unroll
    for (int j = 0; j < 7 - i; ++j) {
      const bool sw = (v[j + 1] > v[j]) || (v[j + 1] == v[j] && si[j + 1] < si[j]);
      const float tv = sw ? v[j + 1] : v[j];
      const int   ti = sw ? si[j + 1] : si[j];
      v[j + 1] = sw ? v[j] : v[j + 1];  si[j + 1] = sw ? si[j] : si[j + 1];
      v[j] = tv;  si[j] = ti;
    }
  const float mxl = v[0];
  double s8 = 1.0;
#pragma unroll
  for (int j = 1; j < 8; ++j) s8 += (double)expf(v[j] - mxl);

  unsigned long long p[8];
#pragma unroll
  for (int j = 0; j < 8; ++j)
    p[j] = ((unsigned long long)ford(v[j]) << 32) | (0xFFFFFFFFu - (unsigned)si[j]);

  for (int r = 0; r < 16; ++r) {
    unsigned long long m = p[0];
#pragma unroll
    for (int off = 1; off < 64; off <<= 1) {
      const unsigned long long o = __shfl_xor(m, off);
      m = (o > m) ? o : m;
    }
    if (lane == 0) cvp[w * 16 + r] = m;
    if (p[0] == m) {
      p[0]=p[1]; p[1]=p[2]; p[2]=p[3]; p[3]=p[4]; p[4]=p[5]; p[5]=p[6]; p[6]=p[7]; p[7]=0ull;
    }
  }
  __syncthreads();

  if (w == 0) {
    const unsigned long long mine = cvp[lane];
    int rank = 0;
#pragma unroll
    for (int j = 0; j < 64; ++j) rank += (cvp[j] > mine);
    if (rank < 16) {
      gci[rank] = (int)(0xFFFFFFFFu - (unsigned)(mine & 0xFFFFFFFFu));
      if (rank == 0) smax_s = finv((unsigned)(mine >> 32));
    }
  }
  __syncthreads();

  const float mx = smax_s;
  double lsum = s8 * (double)expf(mxl - mx);
#pragma unroll
  for (int off = 32; off; off >>= 1) lsum += __shfl_xor(lsum, off);
  if (lane == 0) wsum[w] = lsum;
  __syncthreads();
  if (t == 0) ginv = 1.0 / (wsum[0] + wsum[1] + wsum[2] + wsum[3]);

  const int kb = lane * 16;
  float gwl[16];
  *(float4*)&gwl[0]  = *(const float4*)&gw[(size_t)e * ND + kb];
  *(float4*)&gwl[4]  = *(const float4*)&gw[(size_t)e * ND + kb + 4];
  *(float4*)&gwl[8]  = *(const float4*)&gw[(size_t)e * ND + kb + 8];
  *(float4*)&gwl[12] = *(const float4*)&gw[(size_t)e * ND + kb + 12];
#pragma unroll
  for (int q = 0; q < 4; ++q) {
    const int c = w * 4 + q;
    const int ciq = gci[c];
    const float* xr = x + ((size_t)b * NS + ciq) * ND + kb;
    float xv[16];
    *(float4*)&xv[0]  = *(const float4*)&xr[0];
    *(float4*)&xv[4]  = *(const float4*)&xr[4];
    *(float4*)&xv[8]  = *(const float4*)&xr[8];
    *(float4*)&xv[12] = *(const float4*)&xr[12];
    double d = 0.0;
#pragma unroll
    for (int j2 = 0; j2 < 16; ++j2) d += (double)xv[j2] * (double)gwl[j2];
#pragma unroll
    for (int off = 32; off; off >>= 1) d += __shfl_xor(d, off);
    if (lane == 0) glc[c] = (float)d;
  }
  __syncthreads();
  if (t < 16) {
    const float mylc = glc[t]; const int myci = gci[t];
    int rank = 0;
#pragma unroll
    for (int c2 = 0; c2 < 16; ++c2) {
      if (c2 == t) continue;
      rank += (glc[c2] > mylc) || (glc[c2] == mylc && gci[c2] < myci);
    }
    if (rank < 8) {
      const float pv = (float)((double)expf(mylc - mx) * ginv);
      tval[be * 8 + rank] = pv;
      tidx[be * 8 + rank] = myci;
      selv[rank] = pv;
      seli[rank] = myci;
    }
  }
  __syncthreads();

  // fused mux/merge (rank order, identical to old k_merge)
  float4 acc4 = {0.f, 0.f, 0.f, 0.f};
#pragma unroll
  for (int k = 0; k < 8; ++k) {
    const float vv = selv[k];
    const int   ss = seli[k];
    const float4 xv4 = *(const float4*)&x[((size_t)b * NS + ss) * ND + t * 4];
    acc4.x += vv * xv4.x; acc4.y += vv * xv4.y;
    acc4.z += vv * xv4.z; acc4.w += vv * xv4.w;
  }
  const int kt = t >> 4;
  const int g  = (t & 15) >> 1;
  const size_t off = ((size_t)(e * 16 + kt)) * 4096 + b * 64 + ((g ^ (b & 7)) << 3) + (t & 1) * 4;
  unsigned short h4[4] = {f2bf_rne(acc4.x), f2bf_rne(acc4.y), f2bf_rne(acc4.z), f2bf_rne(acc4.w)};
  *(ushort4*)&A1[off] = *(const ushort4*)h4;
}

// ---------------------------------------------------------------------------
// Kernels 3/4: per-expert FFN GEMM, single-bf16 MFMA, BN=64, 32KB LDS (R9).
// ---------------------------------------------------------------------------
template <int K, int N, bool GELU>
__global__ __launch_bounds__(256, 4) void k_ffn(const unsigned short* __restrict__ AT,
                                                const float* __restrict__ W,
                                                unsigned short* __restrict__ OT,
                                                float* __restrict__ Of) {
  constexpr int KT = K / 64;
  const int e  = blockIdx.y;
  const int n0 = blockIdx.x * 64;
  const int t  = threadIdx.x, l = t & 63, w = t >> 6;
  const int wr = w >> 1, wc = w & 1;

  __shared__ char smem[32768];

  const float* Wbase = W + (size_t)e * (K + 1) * N;
  f32x4 acc[2][2] = {};

  const int wn  = l;
  const int wk0 = w * 8;
  float wreg[2][8];

  auto issueW = [&](int kt) {
    const float* Wg = Wbase + (size_t)(kt * 64) * N + n0 + wn;
#pragma unroll
    for (int rn = 0; rn < 2; ++rn)
#pragma unroll
      for (int j = 0; j < 8; ++j)
        wreg[rn][j] = Wg[(size_t)(wk0 + rn * 32 + j) * N];
  };
  auto issueA = [&](int kt, int dst) {
    const unsigned short* at = AT + ((size_t)(e * KT + kt)) * 4096;
    char* Ab = smem + dst * 8192;
#pragma unroll
    for (int p = 0; p < 2; ++p)
      gload_lds16(at + p * 2048 + t * 8, Ab + p * 4096 + w * 1024);
  };
  auto commitW = [&](int dst) {
    short* Bb = (short*)(smem + 16384 + dst * 8192);
#pragma unroll
    for (int rn = 0; rn < 2; ++rn) {
      const int kr = (wk0 + rn * 32) >> 3;
      unsigned short s8[8];
#pragma unroll
      for (int j = 0; j < 8; ++j) s8[j] = f2bf_rne(wreg[rn][j]);
      *(uint4*)&Bb[wn * 64 + ((kr ^ (wn & 7)) << 3)] = *(const uint4*)s8;
    }
  };
  auto mfma_phase = [&](int cur) {
    const short* Ab = (const short*)(smem + cur * 8192);
    const short* Bb = (const short*)(smem + 16384 + cur * 8192);
#pragma unroll
    for (int ks = 0; ks < 2; ++ks) {
      const int g8 = ks * 4 + (l >> 4);
      bf16x8 a[2], bb[2];
#pragma unroll
      for (int mf = 0; mf < 2; ++mf) {
        const int m = wr * 32 + mf * 16 + (l & 15);
        a[mf] = *(const bf16x8*)&Ab[m * 64 + ((g8 ^ (m & 7)) << 3)];
      }
#pragma unroll
      for (int nf = 0; nf < 2; ++nf) {
        const int n = wc * 32 + nf * 16 + (l & 15);
        bb[nf] = *(const bf16x8*)&Bb[n * 64 + ((g8 ^ (n & 7)) << 3)];
      }
#pragma unroll
      for (int mf = 0; mf < 2; ++mf)
#pragma unroll
        for (int nf = 0; nf < 2; ++nf)
          acc[mf][nf] = __builtin_amdgcn_mfma_f32_16x16x32_bf16(a[mf], bb[nf], acc[mf][nf], 0, 0, 0);
    }
  };

  issueW(0); issueA(0, 0);
  commitW(0);
  __syncthreads();
  int cur = 0;
  for (int kt = 0; kt < KT; ++kt) {
    const bool more = (kt + 1 < KT);
    if (more) { issueW(kt + 1); issueA(kt + 1, cur ^ 1); }
    mfma_phase(cur);
    if (more) commitW(cur ^ 1);
    __syncthreads();
    cur ^= 1;
  }

  if (GELU) {
    unsigned short* transU = (unsigned short*)smem;  // [64][72]
#pragma unroll
    for (int nf = 0; nf < 2; ++nf) {
      const int c = wc * 32 + nf * 16 + (l & 15);
      const float bias = Wbase[(size_t)K * N + n0 + c];
#pragma unroll
      for (int mf = 0; mf < 2; ++mf)
#pragma unroll
        for (int j = 0; j < 4; ++j) {
          const int m = wr * 32 + mf * 16 + (l >> 4) * 4 + j;
          float vv = acc[mf][nf][j] + bias;
          vv = 0.5f * vv * (1.0f + erff(vv * 0.70710678118654752440f));
          transU[m * 72 + c] = f2bf_rne(vv);
        }
    }
    __syncthreads();
    const int m  = t >> 2;
    const int c0 = (t & 3) * 16;
    const size_t tb = ((size_t)(e * (N / 64) + blockIdx.x)) * 4096;
    uint4 v0 = *(const uint4*)&transU[m * 72 + c0];
    uint4 v1 = *(const uint4*)&transU[m * 72 + c0 + 8];
    const int g0 = c0 >> 3;
    *(uint4*)&OT[tb + m * 64 + ((g0 ^ (m & 7)) << 3)]       = v0;
    *(uint4*)&OT[tb + m * 64 + (((g0 + 1) ^ (m & 7)) << 3)] = v1;
  } else {
    float* transF = (float*)smem;  // [64][68]
#pragma unroll
    for (int nf = 0; nf < 2; ++nf) {
      const int c = wc * 32 + nf * 16 + (l & 15);
      const float bias = Wbase[(size_t)K * N + n0 + c];
#pragma unroll
      for (int mf = 0; mf < 2; ++mf)
#pragma unroll
        for (int j = 0; j < 4; ++j) {
          const int m = wr * 32 + mf * 16 + (l >> 4) * 4 + j;
          transF[m * 68 + c] = acc[mf][nf][j] + bias;
        }
    }
    __syncthreads();
    const int m  = t >> 2;
    const int c0 = (t & 3) * 16;
    float* og = Of + ((size_t)m * NE + e) * ND + n0 + c0;
    *(float4*)&og[0]  = *(const float4*)&transF[m * 68 + c0];
    *(float4*)&og[4]  = *(const float4*)&transF[m * 68 + c0 + 4];
    *(float4*)&og[8]  = *(const float4*)&transF[m * 68 + c0 + 8];
    *(float4*)&og[12] = *(const float4*)&transF[m * 68 + c0 + 12];
  }
}

// ---------------------------------------------------------------------------
// Kernel 5: demux/scatter, 8 tokens per block (R9 form).
// ---------------------------------------------------------------------------
__global__ __launch_bounds__(256) void k_scatter(const float* __restrict__ Obuf,
                                                 const float* __restrict__ tval,
                                                 const int* __restrict__ tidx,
                                                 float* __restrict__ out) {
  const int s0 = blockIdx.x * 8;
  const int b  = blockIdx.y;
  const int t  = threadIdx.x;
  const int w  = t >> 6;
  __shared__ unsigned long long masks[8][4];

  const int myIdx = tidx[b * 256 + t];
#pragma unroll
  for (int j = 0; j < 8; ++j) {
    unsigned long long m = __ballot(myIdx == s0 + j);
    if ((t & 63) == 0) masks[j][w] = m;
  }
  __syncthreads();

#pragma unroll
  for (int j = 0; j < 8; ++j) {
    float4 acc = {0.f, 0.f, 0.f, 0.f};
#pragma unroll
    for (int q = 0; q < 4; ++q) {
      unsigned long long mm = masks[j][q];
      while (mm) {
        int bit = __ffsll(mm) - 1;
        mm &= mm - 1;
        int r = q * 64 + bit;
        float v = tval[b * 256 + r];
        const float4 ov = *(const float4*)&Obuf[((size_t)b * NE + (r >> 3)) * ND + t * 4];
        acc.x += v * ov.x; acc.y += v * ov.y; acc.z += v * ov.z; acc.w += v * ov.w;
      }
    }
    *(float4*)&out[((size_t)b * NS + s0 + j) * ND + t * 4] = acc;
  }
}

// ---------------------------------------------------------------------------
extern "C" void kernel_launch(void* const* d_in, const int* in_sizes, int n_in,
                              void* d_out, int out_size, void* d_ws, size_t ws_size,
                              hipStream_t stream) {
  const float* x  = (const float*)d_in[0];
  const float* gw = (const float*)d_in[1];
  const float* w1 = (const float*)d_in[3];
  const float* w2 = (const float*)d_in[4];
  float* out = (float*)d_out;

  char* ws = (char*)d_ws;
  float* logitsT     = (float*)ws;                         // 16,777,216 B
  float* tval        = (float*)(ws + 16777216);            //     65,536 B
  int*   tidx        = (int*)  (ws + 16842752);            //     65,536 B
  unsigned short* A1 = (unsigned short*)(ws + 16908288);   //  4,194,304 B (bf16 tiles)
  unsigned short* Hb = (unsigned short*)(ws + 21102592);   // 16,777,216 B (bf16 tiles)
  float* Obuf        = (float*)(ws + 37879808);            //  8,388,608 B

  k_gate_mfma<<<dim3(NS / 128, NB), 512, 0, stream>>>(x, gw, logitsT);
  k_topk_merge<<<NB * NE, 256, 0, stream>>>(logitsT, x, gw, tval, tidx, A1);
  k_ffn<ND, NH, true ><<<dim3(NH / 64, NE), 256, 0, stream>>>(A1, w1, Hb, nullptr);
  k_ffn<NH, ND, false><<<dim3(ND / 64, NE), 256, 0, stream>>>(Hb, w2, nullptr, Obuf);
  k_scatter<<<dim3(NS / 8, NB), 256, 0, stream>>>(Obuf, tval, tidx, out);
}

// Round 17
// 507.137 us; speedup vs baseline: 1.0660x; 1.0144x over previous
//
#include <hip/hip_runtime.h>
#include <hip/hip_bf16.h>
#include <math.h>

constexpr int NB = 64;     // batch
constexpr int NS = 2048;   // tokens
constexpr int ND = 1024;   // model dim
constexpr int NE = 32;     // experts
constexpr int NH = 4096;   // hidden
constexpr int NK = 8;      // top-k tokens per expert

typedef short bf16x8 __attribute__((ext_vector_type(8)));
typedef float f32x4  __attribute__((ext_vector_type(4)));

__device__ __forceinline__ unsigned short f2bf_rne(float v) {
  unsigned u = __builtin_bit_cast(unsigned, v);
  u += 0x7fffu + ((u >> 16) & 1u);
  return (unsigned short)(u >> 16);
}

__device__ __forceinline__ void gload_lds16(const void* g, void* l) {
  __builtin_amdgcn_global_load_lds(
      (const __attribute__((address_space(1))) unsigned*)g,
      (__attribute__((address_space(3))) unsigned*)l, 16, 0, 0);
}

// order-preserving float->u32 (monotone), and inverse
__device__ __forceinline__ unsigned ford(float f) {
  unsigned u = __builtin_bit_cast(unsigned, f);
  return (u & 0x80000000u) ? ~u : (u | 0x80000000u);
}
__device__ __forceinline__ float finv(unsigned o) {
  unsigned u = (o & 0x80000000u) ? (o & 0x7fffffffu) : ~o;
  return __builtin_bit_cast(float, u);
}

// ---------------------------------------------------------------------------
// Kernel 1: gating GEMM, single-term bf16 MFMA, 64-token tiles, 24KB LDS
// (~6 blocks/CU). T4 pipeline: two register sets, raw s_barrier with
// lgkmcnt-only (no vmcnt drain), x2-unrolled K-loop. (R12/R13 best form.)
// ---------------------------------------------------------------------------
__global__ __launch_bounds__(256) void k_gate_mfma(const float* __restrict__ x,
                                                   const float* __restrict__ gw,
                                                   float* __restrict__ logitsT) {
  const int b  = blockIdx.y;
  const int s0 = blockIdx.x * 64;
  const int t  = threadIdx.x;
  const int l  = t & 63;
  const int w  = t >> 6;

  __shared__ char smem[24576];
  float* trans = (float*)smem;

  f32x4 acc[2] = {};

  const int ar  = t >> 2;
  const int ac4 = (t & 3) * 16;
  const int ge  = t >> 3;
  const int gk  = (t & 7) * 8;

  float xA[4][4], xB[4][4], wA[8], wB[8];

  auto issue = [&](int kt, float (&xreg)[4][4], float (&wreg)[8]) {
    const int k0 = kt * 64;
    const float* xr = &x[((size_t)b * NS + s0 + ar) * ND + k0 + ac4];
#pragma unroll
    for (int j = 0; j < 4; ++j) *(float4*)xreg[j] = *(const float4*)&xr[j * 4];
    *(float4*)&wreg[0] = *(const float4*)&gw[(size_t)ge * ND + k0 + gk];
    *(float4*)&wreg[4] = *(const float4*)&gw[(size_t)ge * ND + k0 + gk + 4];
  };
  auto commit = [&](int dst, float (&xreg)[4][4], float (&wreg)[8]) {
    short* Ah = (short*)(smem + dst * 8192);
    short* Bh = (short*)(smem + 16384 + dst * 4096);
#pragma unroll
    for (int j = 0; j < 4; ++j) {
      unsigned short h[4];
#pragma unroll
      for (int q = 0; q < 4; ++q) h[q] = f2bf_rne(xreg[j][q]);
      const int col = ac4 + j * 4;
      *(ushort4*)&Ah[ar * 64 + (col ^ ((ar & 7) * 8))] = *(const ushort4*)h;
    }
    unsigned short h8[8];
#pragma unroll
    for (int j = 0; j < 8; ++j) h8[j] = f2bf_rne(wreg[j]);
    *(uint4*)&Bh[ge * 64 + (gk ^ ((ge & 7) * 8))] = *(const uint4*)h8;
  };
  auto mfma_phase = [&](int cur) {
    const short* Ah = (const short*)(smem + cur * 8192);
    const short* Bh = (const short*)(smem + 16384 + cur * 4096);
#pragma unroll
    for (int ks = 0; ks < 2; ++ks) {
      const int koff = ks * 32 + (l >> 4) * 8;
      const int rl = w * 16 + (l & 15);
      bf16x8 a = *(const bf16x8*)&Ah[rl * 64 + (koff ^ ((rl & 7) * 8))];
#pragma unroll
      for (int nf = 0; nf < 2; ++nf) {
        const int n = nf * 16 + (l & 15);
        bf16x8 bb = *(const bf16x8*)&Bh[n * 64 + (koff ^ ((n & 7) * 8))];
        acc[nf] = __builtin_amdgcn_mfma_f32_16x16x32_bf16(a, bb, acc[nf], 0, 0, 0);
      }
    }
  };
  auto bar = [&]() {
    asm volatile("s_waitcnt lgkmcnt(0)" ::: "memory");
    __builtin_amdgcn_s_barrier();
    __builtin_amdgcn_sched_barrier(0);
  };

  issue(0, xA, wA);
  issue(1, xB, wB);
  commit(0, xA, wA);
  bar();

  for (int kt = 0; kt < ND / 64; kt += 2) {
    if (kt + 2 < ND / 64) issue(kt + 2, xA, wA);
    commit(1, xB, wB);
    mfma_phase(0);
    bar();
    if (kt + 3 < ND / 64) issue(kt + 3, xB, wB);
    if (kt + 2 < ND / 64) commit(0, xA, wA);
    mfma_phase(1);
    bar();
  }

  // transpose epilogue through LDS for coalesced [e][s] stores
#pragma unroll
  for (int nf = 0; nf < 2; ++nf)
#pragma unroll
    for (int j = 0; j < 4; ++j) {
      const int sl = w * 16 + (l >> 4) * 4 + j;
      const int ec = nf * 16 + (l & 15);
      trans[sl * 33 + ec] = acc[nf][j];
    }
  __syncthreads();
  const int eo = t >> 3, sc = (t & 7) * 8;
#pragma unroll
  for (int q = 0; q < 2; ++q) {
    float4 v;
    v.x = trans[(sc + q * 4 + 0) * 33 + eo];
    v.y = trans[(sc + q * 4 + 1) * 33 + eo];
    v.z = trans[(sc + q * 4 + 2) * 33 + eo];
    v.w = trans[(sc + q * 4 + 3) * 33 + eo];
    *(float4*)&logitsT[((size_t)b * NE + eo) * NS + s0 + sc + q * 4] = v;
  }
}

// ---------------------------------------------------------------------------
// Kernel 2: topk + FUSED merge (R13, unchanged).
// ---------------------------------------------------------------------------
__global__ __launch_bounds__(256) void k_topk_merge(const float* __restrict__ logitsT,
                                                    const float* __restrict__ x,
                                                    const float* __restrict__ gw,
                                                    float* __restrict__ tval,
                                                    int* __restrict__ tidx,
                                                    unsigned short* __restrict__ A1) {
  const int be = blockIdx.x, b = be >> 5, e = be & 31;
  const float* row = logitsT + (size_t)be * NS;
  const int t = threadIdx.x, w = t >> 6, lane = t & 63;

  __shared__ unsigned long long cvp[64];
  __shared__ int    gci[16];
  __shared__ float  glc[16];
  __shared__ double wsum[4];
  __shared__ float  smax_s;
  __shared__ double ginv;
  __shared__ float  selv[8];
  __shared__ int    seli[8];

  float v[8]; int si[8];
#pragma unroll
  for (int j = 0; j < 8; ++j) {
    const int s = w * 512 + lane + j * 64;
    v[j] = row[s]; si[j] = s;
  }
#pragma unroll
  for (int i = 0; i < 7; ++i)
#pragma unroll
    for (int j = 0; j < 7 - i; ++j) {
      const bool sw = (v[j + 1] > v[j]) || (v[j + 1] == v[j] && si[j + 1] < si[j]);
      const float tv = sw ? v[j + 1] : v[j];
      const int   ti = sw ? si[j + 1] : si[j];
      v[j + 1] = sw ? v[j] : v[j + 1];  si[j + 1] = sw ? si[j] : si[j + 1];
      v[j] = tv;  si[j] = ti;
    }
  const float mxl = v[0];
  double s8 = 1.0;
#pragma unroll
  for (int j = 1; j < 8; ++j) s8 += (double)expf(v[j] - mxl);

  unsigned long long p[8];
#pragma unroll
  for (int j = 0; j < 8; ++j)
    p[j] = ((unsigned long long)ford(v[j]) << 32) | (0xFFFFFFFFu - (unsigned)si[j]);

  for (int r = 0; r < 16; ++r) {
    unsigned long long m = p[0];
#pragma unroll
    for (int off = 1; off < 64; off <<= 1) {
      const unsigned long long o = __shfl_xor(m, off);
      m = (o > m) ? o : m;
    }
    if (lane == 0) cvp[w * 16 + r] = m;
    if (p[0] == m) {
      p[0]=p[1]; p[1]=p[2]; p[2]=p[3]; p[3]=p[4]; p[4]=p[5]; p[5]=p[6]; p[6]=p[7]; p[7]=0ull;
    }
  }
  __syncthreads();

  if (w == 0) {
    const unsigned long long mine = cvp[lane];
    int rank = 0;
#pragma unroll
    for (int j = 0; j < 64; ++j) rank += (cvp[j] > mine);
    if (rank < 16) {
      gci[rank] = (int)(0xFFFFFFFFu - (unsigned)(mine & 0xFFFFFFFFu));
      if (rank == 0) smax_s = finv((unsigned)(mine >> 32));
    }
  }
  __syncthreads();

  const float mx = smax_s;
  double lsum = s8 * (double)expf(mxl - mx);
#pragma unroll
  for (int off = 32; off; off >>= 1) lsum += __shfl_xor(lsum, off);
  if (lane == 0) wsum[w] = lsum;
  __syncthreads();
  if (t == 0) ginv = 1.0 / (wsum[0] + wsum[1] + wsum[2] + wsum[3]);

  const int kb = lane * 16;
  float gwl[16];
  *(float4*)&gwl[0]  = *(const float4*)&gw[(size_t)e * ND + kb];
  *(float4*)&gwl[4]  = *(const float4*)&gw[(size_t)e * ND + kb + 4];
  *(float4*)&gwl[8]  = *(const float4*)&gw[(size_t)e * ND + kb + 8];
  *(float4*)&gwl[12] = *(const float4*)&gw[(size_t)e * ND + kb + 12];
#pragma unroll
  for (int q = 0; q < 4; ++q) {
    const int c = w * 4 + q;
    const int ciq = gci[c];
    const float* xr = x + ((size_t)b * NS + ciq) * ND + kb;
    float xv[16];
    *(float4*)&xv[0]  = *(const float4*)&xr[0];
    *(float4*)&xv[4]  = *(const float4*)&xr[4];
    *(float4*)&xv[8]  = *(const float4*)&xr[8];
    *(float4*)&xv[12] = *(const float4*)&xr[12];
    double d = 0.0;
#pragma unroll
    for (int j2 = 0; j2 < 16; ++j2) d += (double)xv[j2] * (double)gwl[j2];
#pragma unroll
    for (int off = 32; off; off >>= 1) d += __shfl_xor(d, off);
    if (lane == 0) glc[c] = (float)d;
  }
  __syncthreads();
  if (t < 16) {
    const float mylc = glc[t]; const int myci = gci[t];
    int rank = 0;
#pragma unroll
    for (int c2 = 0; c2 < 16; ++c2) {
      if (c2 == t) continue;
      rank += (glc[c2] > mylc) || (glc[c2] == mylc && gci[c2] < myci);
    }
    if (rank < 8) {
      const float pv = (float)((double)expf(mylc - mx) * ginv);
      tval[be * 8 + rank] = pv;
      tidx[be * 8 + rank] = myci;
      selv[rank] = pv;
      seli[rank] = myci;
    }
  }
  __syncthreads();

  // fused mux/merge (rank order, identical to old k_merge)
  float4 acc4 = {0.f, 0.f, 0.f, 0.f};
#pragma unroll
  for (int k = 0; k < 8; ++k) {
    const float vv = selv[k];
    const int   ss = seli[k];
    const float4 xv4 = *(const float4*)&x[((size_t)b * NS + ss) * ND + t * 4];
    acc4.x += vv * xv4.x; acc4.y += vv * xv4.y;
    acc4.z += vv * xv4.z; acc4.w += vv * xv4.w;
  }
  const int kt = t >> 4;
  const int g  = (t & 15) >> 1;
  const size_t off = ((size_t)(e * 16 + kt)) * 4096 + b * 64 + ((g ^ (b & 7)) << 3) + (t & 1) * 4;
  unsigned short h4[4] = {f2bf_rne(acc4.x), f2bf_rne(acc4.y), f2bf_rne(acc4.z), f2bf_rne(acc4.w)};
  *(ushort4*)&A1[off] = *(const ushort4*)h4;
}

// ---------------------------------------------------------------------------
// Kernels 3/4: per-expert FFN GEMM, single-bf16 MFMA, BN=64, 32KB LDS (R9).
// ---------------------------------------------------------------------------
template <int K, int N, bool GELU>
__global__ __launch_bounds__(256, 4) void k_ffn(const unsigned short* __restrict__ AT,
                                                const float* __restrict__ W,
                                                unsigned short* __restrict__ OT,
                                                float* __restrict__ Of) {
  constexpr int KT = K / 64;
  const int e  = blockIdx.y;
  const int n0 = blockIdx.x * 64;
  const int t  = threadIdx.x, l = t & 63, w = t >> 6;
  const int wr = w >> 1, wc = w & 1;

  __shared__ char smem[32768];

  const float* Wbase = W + (size_t)e * (K + 1) * N;
  f32x4 acc[2][2] = {};

  const int wn  = l;
  const int wk0 = w * 8;
  float wreg[2][8];

  auto issueW = [&](int kt) {
    const float* Wg = Wbase + (size_t)(kt * 64) * N + n0 + wn;
#pragma unroll
    for (int rn = 0; rn < 2; ++rn)
#pragma unroll
      for (int j = 0; j < 8; ++j)
        wreg[rn][j] = Wg[(size_t)(wk0 + rn * 32 + j) * N];
  };
  auto issueA = [&](int kt, int dst) {
    const unsigned short* at = AT + ((size_t)(e * KT + kt)) * 4096;
    char* Ab = smem + dst * 8192;
#pragma unroll
    for (int p = 0; p < 2; ++p)
      gload_lds16(at + p * 2048 + t * 8, Ab + p * 4096 + w * 1024);
  };
  auto commitW = [&](int dst) {
    short* Bb = (short*)(smem + 16384 + dst * 8192);
#pragma unroll
    for (int rn = 0; rn < 2; ++rn) {
      const int kr = (wk0 + rn * 32) >> 3;
      unsigned short s8[8];
#pragma unroll
      for (int j = 0; j < 8; ++j) s8[j] = f2bf_rne(wreg[rn][j]);
      *(uint4*)&Bb[wn * 64 + ((kr ^ (wn & 7)) << 3)] = *(const uint4*)s8;
    }
  };
  auto mfma_phase = [&](int cur) {
    const short* Ab = (const short*)(smem + cur * 8192);
    const short* Bb = (const short*)(smem + 16384 + cur * 8192);
#pragma unroll
    for (int ks = 0; ks < 2; ++ks) {
      const int g8 = ks * 4 + (l >> 4);
      bf16x8 a[2], bb[2];
#pragma unroll
      for (int mf = 0; mf < 2; ++mf) {
        const int m = wr * 32 + mf * 16 + (l & 15);
        a[mf] = *(const bf16x8*)&Ab[m * 64 + ((g8 ^ (m & 7)) << 3)];
      }
#pragma unroll
      for (int nf = 0; nf < 2; ++nf) {
        const int n = wc * 32 + nf * 16 + (l & 15);
        bb[nf] = *(const bf16x8*)&Bb[n * 64 + ((g8 ^ (n & 7)) << 3)];
      }
#pragma unroll
      for (int mf = 0; mf < 2; ++mf)
#pragma unroll
        for (int nf = 0; nf < 2; ++nf)
          acc[mf][nf] = __builtin_amdgcn_mfma_f32_16x16x32_bf16(a[mf], bb[nf], acc[mf][nf], 0, 0, 0);
    }
  };

  issueW(0); issueA(0, 0);
  commitW(0);
  __syncthreads();
  int cur = 0;
  for (int kt = 0; kt < KT; ++kt) {
    const bool more = (kt + 1 < KT);
    if (more) { issueW(kt + 1); issueA(kt + 1, cur ^ 1); }
    mfma_phase(cur);
    if (more) commitW(cur ^ 1);
    __syncthreads();
    cur ^= 1;
  }

  if (GELU) {
    unsigned short* transU = (unsigned short*)smem;  // [64][72]
#pragma unroll
    for (int nf = 0; nf < 2; ++nf) {
      const int c = wc * 32 + nf * 16 + (l & 15);
      const float bias = Wbase[(size_t)K * N + n0 + c];
#pragma unroll
      for (int mf = 0; mf < 2; ++mf)
#pragma unroll
        for (int j = 0; j < 4; ++j) {
          const int m = wr * 32 + mf * 16 + (l >> 4) * 4 + j;
          float vv = acc[mf][nf][j] + bias;
          vv = 0.5f * vv * (1.0f + erff(vv * 0.70710678118654752440f));
          transU[m * 72 + c] = f2bf_rne(vv);
        }
    }
    __syncthreads();
    const int m  = t >> 2;
    const int c0 = (t & 3) * 16;
    const size_t tb = ((size_t)(e * (N / 64) + blockIdx.x)) * 4096;
    uint4 v0 = *(const uint4*)&transU[m * 72 + c0];
    uint4 v1 = *(const uint4*)&transU[m * 72 + c0 + 8];
    const int g0 = c0 >> 3;
    *(uint4*)&OT[tb + m * 64 + ((g0 ^ (m & 7)) << 3)]       = v0;
    *(uint4*)&OT[tb + m * 64 + (((g0 + 1) ^ (m & 7)) << 3)] = v1;
  } else {
    float* transF = (float*)smem;  // [64][68]
#pragma unroll
    for (int nf = 0; nf < 2; ++nf) {
      const int c = wc * 32 + nf * 16 + (l & 15);
      const float bias = Wbase[(size_t)K * N + n0 + c];
#pragma unroll
      for (int mf = 0; mf < 2; ++mf)
#pragma unroll
        for (int j = 0; j < 4; ++j) {
          const int m = wr * 32 + mf * 16 + (l >> 4) * 4 + j;
          transF[m * 68 + c] = acc[mf][nf][j] + bias;
        }
    }
    __syncthreads();
    const int m  = t >> 2;
    const int c0 = (t & 3) * 16;
    float* og = Of + ((size_t)m * NE + e) * ND + n0 + c0;
    *(float4*)&og[0]  = *(const float4*)&transF[m * 68 + c0];
    *(float4*)&og[4]  = *(const float4*)&transF[m * 68 + c0 + 4];
    *(float4*)&og[8]  = *(const float4*)&transF[m * 68 + c0 + 8];
    *(float4*)&og[12] = *(const float4*)&transF[m * 68 + c0 + 12];
  }
}

// ---------------------------------------------------------------------------
// Kernel 5: demux/scatter, 8 tokens per block; deterministic fixed-order
// accumulation; zero-fills unpicked tokens.
// ---------------------------------------------------------------------------
__global__ __launch_bounds__(256) void k_scatter(const float* __restrict__ Obuf,
                                                 const float* __restrict__ tval,
                                                 const int* __restrict__ tidx,
                                                 float* __restrict__ out) {
  const int s0 = blockIdx.x * 8;
  const int b  = blockIdx.y;
  const int t  = threadIdx.x;
  const int w  = t >> 6;
  __shared__ unsigned long long masks[8][4];

  const int myIdx = tidx[b * 256 + t];
#pragma unroll
  for (int j = 0; j < 8; ++j) {
    unsigned long long m = __ballot(myIdx == s0 + j);
    if ((t & 63) == 0) masks[j][w] = m;
  }
  __syncthreads();

#pragma unroll
  for (int j = 0; j < 8; ++j) {
    float4 acc = {0.f, 0.f, 0.f, 0.f};
#pragma unroll
    for (int q = 0; q < 4; ++q) {
      unsigned long long mm = masks[j][q];
      while (mm) {
        int bit = __ffsll(mm) - 1;
        mm &= mm - 1;
        int r = q * 64 + bit;
        float v = tval[b * 256 + r];
        const float4 ov = *(const float4*)&Obuf[((size_t)b * NE + (r >> 3)) * ND + t * 4];
        acc.x += v * ov.x; acc.y += v * ov.y; acc.z += v * ov.z; acc.w += v * ov.w;
      }
    }
    *(float4*)&out[((size_t)b * NS + s0 + j) * ND + t * 4] = acc;
  }
}

// ---------------------------------------------------------------------------
extern "C" void kernel_launch(void* const* d_in, const int* in_sizes, int n_in,
                              void* d_out, int out_size, void* d_ws, size_t ws_size,
                              hipStream_t stream) {
  const float* x  = (const float*)d_in[0];
  const float* gw = (const float*)d_in[1];
  const float* w1 = (const float*)d_in[3];
  const float* w2 = (const float*)d_in[4];
  float* out = (float*)d_out;

  char* ws = (char*)d_ws;
  float* logitsT     = (float*)ws;                         // 16,777,216 B
  float* tval        = (float*)(ws + 16777216);            //     65,536 B
  int*   tidx        = (int*)  (ws + 16842752);            //     65,536 B
  unsigned short* A1 = (unsigned short*)(ws + 16908288);   //  4,194,304 B (bf16 tiles)
  unsigned short* Hb = (unsigned short*)(ws + 21102592);   // 16,777,216 B (bf16 tiles)
  float* Obuf        = (float*)(ws + 37879808);            //  8,388,608 B

  k_gate_mfma<<<dim3(NS / 64, NB), 256, 0, stream>>>(x, gw, logitsT);
  k_topk_merge<<<NB * NE, 256, 0, stream>>>(logitsT, x, gw, tval, tidx, A1);
  k_ffn<ND, NH, true ><<<dim3(NH / 64, NE), 256, 0, stream>>>(A1, w1, Hb, nullptr);
  k_ffn<NH, ND, false><<<dim3(ND / 64, NE), 256, 0, stream>>>(Hb, w2, nullptr, Obuf);
  k_scatter<<<dim3(NS / 8, NB), 256, 0, stream>>>(Obuf, tval, tidx, out);
}

// Round 18
// 497.776 us; speedup vs baseline: 1.0860x; 1.0188x over previous
//
#include <hip/hip_runtime.h>
#include <hip/hip_bf16.h>
#include <math.h>

constexpr int NB = 64;     // batch
constexpr int NS = 2048;   // tokens
constexpr int ND = 1024;   // model dim
constexpr int NE = 32;     // experts
constexpr int NH = 4096;   // hidden
constexpr int NK = 8;      // top-k tokens per expert

typedef short bf16x8 __attribute__((ext_vector_type(8)));
typedef float f32x4  __attribute__((ext_vector_type(4)));

__device__ __forceinline__ unsigned short f2bf_rne(float v) {
  unsigned u = __builtin_bit_cast(unsigned, v);
  u += 0x7fffu + ((u >> 16) & 1u);
  return (unsigned short)(u >> 16);
}

__device__ __forceinline__ void gload_lds16(const void* g, void* l) {
  __builtin_amdgcn_global_load_lds(
      (const __attribute__((address_space(1))) unsigned*)g,
      (__attribute__((address_space(3))) unsigned*)l, 16, 0, 0);
}

// order-preserving float->u32 (monotone), and inverse
__device__ __forceinline__ unsigned ford(float f) {
  unsigned u = __builtin_bit_cast(unsigned, f);
  return (u & 0x80000000u) ? ~u : (u | 0x80000000u);
}
__device__ __forceinline__ float finv(unsigned o) {
  unsigned u = (o & 0x80000000u) ? (o & 0x7fffffffu) : ~o;
  return __builtin_bit_cast(float, u);
}

// ---------------------------------------------------------------------------
// Kernel 1: gating GEMM, single-term bf16 MFMA, 64-token tiles, 24KB LDS
// (~6 blocks/CU). T4 pipeline: two register sets, raw s_barrier with
// lgkmcnt-only (no vmcnt drain), x2-unrolled K-loop. (R12/R13 best form.)
// ---------------------------------------------------------------------------
__global__ __launch_bounds__(256) void k_gate_mfma(const float* __restrict__ x,
                                                   const float* __restrict__ gw,
                                                   float* __restrict__ logitsT) {
  const int b  = blockIdx.y;
  const int s0 = blockIdx.x * 64;
  const int t  = threadIdx.x;
  const int l  = t & 63;
  const int w  = t >> 6;

  __shared__ char smem[24576];
  float* trans = (float*)smem;

  f32x4 acc[2] = {};

  const int ar  = t >> 2;
  const int ac4 = (t & 3) * 16;
  const int ge  = t >> 3;
  const int gk  = (t & 7) * 8;

  float xA[4][4], xB[4][4], wA[8], wB[8];

  auto issue = [&](int kt, float (&xreg)[4][4], float (&wreg)[8]) {
    const int k0 = kt * 64;
    const float* xr = &x[((size_t)b * NS + s0 + ar) * ND + k0 + ac4];
#pragma unroll
    for (int j = 0; j < 4; ++j) *(float4*)xreg[j] = *(const float4*)&xr[j * 4];
    *(float4*)&wreg[0] = *(const float4*)&gw[(size_t)ge * ND + k0 + gk];
    *(float4*)&wreg[4] = *(const float4*)&gw[(size_t)ge * ND + k0 + gk + 4];
  };
  auto commit = [&](int dst, float (&xreg)[4][4], float (&wreg)[8]) {
    short* Ah = (short*)(smem + dst * 8192);
    short* Bh = (short*)(smem + 16384 + dst * 4096);
#pragma unroll
    for (int j = 0; j < 4; ++j) {
      unsigned short h[4];
#pragma unroll
      for (int q = 0; q < 4; ++q) h[q] = f2bf_rne(xreg[j][q]);
      const int col = ac4 + j * 4;
      *(ushort4*)&Ah[ar * 64 + (col ^ ((ar & 7) * 8))] = *(const ushort4*)h;
    }
    unsigned short h8[8];
#pragma unroll
    for (int j = 0; j < 8; ++j) h8[j] = f2bf_rne(wreg[j]);
    *(uint4*)&Bh[ge * 64 + (gk ^ ((ge & 7) * 8))] = *(const uint4*)h8;
  };
  auto mfma_phase = [&](int cur) {
    const short* Ah = (const short*)(smem + cur * 8192);
    const short* Bh = (const short*)(smem + 16384 + cur * 4096);
#pragma unroll
    for (int ks = 0; ks < 2; ++ks) {
      const int koff = ks * 32 + (l >> 4) * 8;
      const int rl = w * 16 + (l & 15);
      bf16x8 a = *(const bf16x8*)&Ah[rl * 64 + (koff ^ ((rl & 7) * 8))];
#pragma unroll
      for (int nf = 0; nf < 2; ++nf) {
        const int n = nf * 16 + (l & 15);
        bf16x8 bb = *(const bf16x8*)&Bh[n * 64 + (koff ^ ((n & 7) * 8))];
        acc[nf] = __builtin_amdgcn_mfma_f32_16x16x32_bf16(a, bb, acc[nf], 0, 0, 0);
      }
    }
  };
  auto bar = [&]() {
    asm volatile("s_waitcnt lgkmcnt(0)" ::: "memory");
    __builtin_amdgcn_s_barrier();
    __builtin_amdgcn_sched_barrier(0);
  };

  issue(0, xA, wA);
  issue(1, xB, wB);
  commit(0, xA, wA);
  bar();

  for (int kt = 0; kt < ND / 64; kt += 2) {
    if (kt + 2 < ND / 64) issue(kt + 2, xA, wA);
    commit(1, xB, wB);
    mfma_phase(0);
    bar();
    if (kt + 3 < ND / 64) issue(kt + 3, xB, wB);
    if (kt + 2 < ND / 64) commit(0, xA, wA);
    mfma_phase(1);
    bar();
  }

  // transpose epilogue through LDS for coalesced [e][s] stores
#pragma unroll
  for (int nf = 0; nf < 2; ++nf)
#pragma unroll
    for (int j = 0; j < 4; ++j) {
      const int sl = w * 16 + (l >> 4) * 4 + j;
      const int ec = nf * 16 + (l & 15);
      trans[sl * 33 + ec] = acc[nf][j];
    }
  __syncthreads();
  const int eo = t >> 3, sc = (t & 7) * 8;
#pragma unroll
  for (int q = 0; q < 2; ++q) {
    float4 v;
    v.x = trans[(sc + q * 4 + 0) * 33 + eo];
    v.y = trans[(sc + q * 4 + 1) * 33 + eo];
    v.z = trans[(sc + q * 4 + 2) * 33 + eo];
    v.w = trans[(sc + q * 4 + 3) * 33 + eo];
    *(float4*)&logitsT[((size_t)b * NE + eo) * NS + s0 + sc + q * 4] = v;
  }
}

// ---------------------------------------------------------------------------
// Kernel 2: topk + FUSED merge. Per-wave top-12 (each lane holds ALL 8 of its
// wave's tokens -> exact per-wave top-K; 12 gives >=4 near-tie crossing
// tolerance for the exact-top-8-superset property). Merge pool 48 -> approx
// top-16 -> fp64 recheck -> exact top-8 + mux (outputs identical to R13).
// ---------------------------------------------------------------------------
__global__ __launch_bounds__(256) void k_topk_merge(const float* __restrict__ logitsT,
                                                    const float* __restrict__ x,
                                                    const float* __restrict__ gw,
                                                    float* __restrict__ tval,
                                                    int* __restrict__ tidx,
                                                    unsigned short* __restrict__ A1) {
  const int be = blockIdx.x, b = be >> 5, e = be & 31;
  const float* row = logitsT + (size_t)be * NS;
  const int t = threadIdx.x, w = t >> 6, lane = t & 63;

  __shared__ unsigned long long cvp[48];   // per-wave top-12 packed
  __shared__ int    gci[16];
  __shared__ float  glc[16];
  __shared__ double wsum[4];
  __shared__ float  smax_s;
  __shared__ double ginv;
  __shared__ float  selv[8];
  __shared__ int    seli[8];

  float v[8]; int si[8];
#pragma unroll
  for (int j = 0; j < 8; ++j) {
    const int s = w * 512 + lane + j * 64;
    v[j] = row[s]; si[j] = s;
  }
#pragma unroll
  for (int i = 0; i < 7; ++i)
#pragma unroll
    for (int j = 0; j < 7 - i; ++j) {
      const bool sw = (v[j + 1] > v[j]) || (v[j + 1] == v[j] && si[j + 1] < si[j]);
      const float tv = sw ? v[j + 1] : v[j];
      const int   ti = sw ? si[j + 1] : si[j];
      v[j + 1] = sw ? v[j] : v[j + 1];  si[j + 1] = sw ? si[j] : si[j + 1];
      v[j] = tv;  si[j] = ti;
    }
  const float mxl = v[0];
  double s8 = 1.0;
#pragma unroll
  for (int j = 1; j < 8; ++j) s8 += (double)expf(v[j] - mxl);

  unsigned long long p[8];
#pragma unroll
  for (int j = 0; j < 8; ++j)
    p[j] = ((unsigned long long)ford(v[j]) << 32) | (0xFFFFFFFFu - (unsigned)si[j]);

  // per-wave top-12 by argmax-pop (keys unique; lanes hold complete lists)
  for (int r = 0; r < 12; ++r) {
    unsigned long long m = p[0];
#pragma unroll
    for (int off = 1; off < 64; off <<= 1) {
      const unsigned long long o = __shfl_xor(m, off);
      m = (o > m) ? o : m;
    }
    if (lane == 0) cvp[w * 12 + r] = m;
    if (p[0] == m) {
      p[0]=p[1]; p[1]=p[2]; p[2]=p[3]; p[3]=p[4]; p[4]=p[5]; p[5]=p[6]; p[6]=p[7]; p[7]=0ull;
    }
  }
  __syncthreads();

  // 48 -> 16 merge: parallel rank-select (wave 0, lanes 0..47)
  if (w == 0 && lane < 48) {
    const unsigned long long mine = cvp[lane];
    int rank = 0;
#pragma unroll
    for (int j = 0; j < 48; ++j) rank += (cvp[j] > mine);
    if (rank < 16) {
      gci[rank] = (int)(0xFFFFFFFFu - (unsigned)(mine & 0xFFFFFFFFu));
      if (rank == 0) smax_s = finv((unsigned)(mine >> 32));
    }
  }
  __syncthreads();

  const float mx = smax_s;
  double lsum = s8 * (double)expf(mxl - mx);
#pragma unroll
  for (int off = 32; off; off >>= 1) lsum += __shfl_xor(lsum, off);
  if (lane == 0) wsum[w] = lsum;
  __syncthreads();
  if (t == 0) ginv = 1.0 / (wsum[0] + wsum[1] + wsum[2] + wsum[3]);

  const int kb = lane * 16;
  float gwl[16];
  *(float4*)&gwl[0]  = *(const float4*)&gw[(size_t)e * ND + kb];
  *(float4*)&gwl[4]  = *(const float4*)&gw[(size_t)e * ND + kb + 4];
  *(float4*)&gwl[8]  = *(const float4*)&gw[(size_t)e * ND + kb + 8];
  *(float4*)&gwl[12] = *(const float4*)&gw[(size_t)e * ND + kb + 12];
#pragma unroll
  for (int q = 0; q < 4; ++q) {
    const int c = w * 4 + q;
    const int ciq = gci[c];
    const float* xr = x + ((size_t)b * NS + ciq) * ND + kb;
    float xv[16];
    *(float4*)&xv[0]  = *(const float4*)&xr[0];
    *(float4*)&xv[4]  = *(const float4*)&xr[4];
    *(float4*)&xv[8]  = *(const float4*)&xr[8];
    *(float4*)&xv[12] = *(const float4*)&xr[12];
    double d = 0.0;
#pragma unroll
    for (int j2 = 0; j2 < 16; ++j2) d += (double)xv[j2] * (double)gwl[j2];
#pragma unroll
    for (int off = 32; off; off >>= 1) d += __shfl_xor(d, off);
    if (lane == 0) glc[c] = (float)d;
  }
  __syncthreads();
  if (t < 16) {
    const float mylc = glc[t]; const int myci = gci[t];
    int rank = 0;
#pragma unroll
    for (int c2 = 0; c2 < 16; ++c2) {
      if (c2 == t) continue;
      rank += (glc[c2] > mylc) || (glc[c2] == mylc && gci[c2] < myci);
    }
    if (rank < 8) {
      const float pv = (float)((double)expf(mylc - mx) * ginv);
      tval[be * 8 + rank] = pv;
      tidx[be * 8 + rank] = myci;
      selv[rank] = pv;
      seli[rank] = myci;
    }
  }
  __syncthreads();

  // fused mux/merge (rank order, identical to old k_merge)
  float4 acc4 = {0.f, 0.f, 0.f, 0.f};
#pragma unroll
  for (int k = 0; k < 8; ++k) {
    const float vv = selv[k];
    const int   ss = seli[k];
    const float4 xv4 = *(const float4*)&x[((size_t)b * NS + ss) * ND + t * 4];
    acc4.x += vv * xv4.x; acc4.y += vv * xv4.y;
    acc4.z += vv * xv4.z; acc4.w += vv * xv4.w;
  }
  const int kt = t >> 4;
  const int g  = (t & 15) >> 1;
  const size_t off = ((size_t)(e * 16 + kt)) * 4096 + b * 64 + ((g ^ (b & 7)) << 3) + (t & 1) * 4;
  unsigned short h4[4] = {f2bf_rne(acc4.x), f2bf_rne(acc4.y), f2bf_rne(acc4.z), f2bf_rne(acc4.w)};
  *(ushort4*)&A1[off] = *(const ushort4*)h4;
}

// ---------------------------------------------------------------------------
// Kernels 3/4: per-expert FFN GEMM, single-bf16 MFMA, BN=64, 32KB LDS (R9).
// ---------------------------------------------------------------------------
template <int K, int N, bool GELU>
__global__ __launch_bounds__(256, 4) void k_ffn(const unsigned short* __restrict__ AT,
                                                const float* __restrict__ W,
                                                unsigned short* __restrict__ OT,
                                                float* __restrict__ Of) {
  constexpr int KT = K / 64;
  const int e  = blockIdx.y;
  const int n0 = blockIdx.x * 64;
  const int t  = threadIdx.x, l = t & 63, w = t >> 6;
  const int wr = w >> 1, wc = w & 1;

  __shared__ char smem[32768];

  const float* Wbase = W + (size_t)e * (K + 1) * N;
  f32x4 acc[2][2] = {};

  const int wn  = l;
  const int wk0 = w * 8;
  float wreg[2][8];

  auto issueW = [&](int kt) {
    const float* Wg = Wbase + (size_t)(kt * 64) * N + n0 + wn;
#pragma unroll
    for (int rn = 0; rn < 2; ++rn)
#pragma unroll
      for (int j = 0; j < 8; ++j)
        wreg[rn][j] = Wg[(size_t)(wk0 + rn * 32 + j) * N];
  };
  auto issueA = [&](int kt, int dst) {
    const unsigned short* at = AT + ((size_t)(e * KT + kt)) * 4096;
    char* Ab = smem + dst * 8192;
#pragma unroll
    for (int p = 0; p < 2; ++p)
      gload_lds16(at + p * 2048 + t * 8, Ab + p * 4096 + w * 1024);
  };
  auto commitW = [&](int dst) {
    short* Bb = (short*)(smem + 16384 + dst * 8192);
#pragma unroll
    for (int rn = 0; rn < 2; ++rn) {
      const int kr = (wk0 + rn * 32) >> 3;
      unsigned short s8[8];
#pragma unroll
      for (int j = 0; j < 8; ++j) s8[j] = f2bf_rne(wreg[rn][j]);
      *(uint4*)&Bb[wn * 64 + ((kr ^ (wn & 7)) << 3)] = *(const uint4*)s8;
    }
  };
  auto mfma_phase = [&](int cur) {
    const short* Ab = (const short*)(smem + cur * 8192);
    const short* Bb = (const short*)(smem + 16384 + cur * 8192);
#pragma unroll
    for (int ks = 0; ks < 2; ++ks) {
      const int g8 = ks * 4 + (l >> 4);
      bf16x8 a[2], bb[2];
#pragma unroll
      for (int mf = 0; mf < 2; ++mf) {
        const int m = wr * 32 + mf * 16 + (l & 15);
        a[mf] = *(const bf16x8*)&Ab[m * 64 + ((g8 ^ (m & 7)) << 3)];
      }
#pragma unroll
      for (int nf = 0; nf < 2; ++nf) {
        const int n = wc * 32 + nf * 16 + (l & 15);
        bb[nf] = *(const bf16x8*)&Bb[n * 64 + ((g8 ^ (n & 7)) << 3)];
      }
#pragma unroll
      for (int mf = 0; mf < 2; ++mf)
#pragma unroll
        for (int nf = 0; nf < 2; ++nf)
          acc[mf][nf] = __builtin_amdgcn_mfma_f32_16x16x32_bf16(a[mf], bb[nf], acc[mf][nf], 0, 0, 0);
    }
  };

  issueW(0); issueA(0, 0);
  commitW(0);
  __syncthreads();
  int cur = 0;
  for (int kt = 0; kt < KT; ++kt) {
    const bool more = (kt + 1 < KT);
    if (more) { issueW(kt + 1); issueA(kt + 1, cur ^ 1); }
    mfma_phase(cur);
    if (more) commitW(cur ^ 1);
    __syncthreads();
    cur ^= 1;
  }

  if (GELU) {
    unsigned short* transU = (unsigned short*)smem;  // [64][72]
#pragma unroll
    for (int nf = 0; nf < 2; ++nf) {
      const int c = wc * 32 + nf * 16 + (l & 15);
      const float bias = Wbase[(size_t)K * N + n0 + c];
#pragma unroll
      for (int mf = 0; mf < 2; ++mf)
#pragma unroll
        for (int j = 0; j < 4; ++j) {
          const int m = wr * 32 + mf * 16 + (l >> 4) * 4 + j;
          float vv = acc[mf][nf][j] + bias;
          vv = 0.5f * vv * (1.0f + erff(vv * 0.70710678118654752440f));
          transU[m * 72 + c] = f2bf_rne(vv);
        }
    }
    __syncthreads();
    const int m  = t >> 2;
    const int c0 = (t & 3) * 16;
    const size_t tb = ((size_t)(e * (N / 64) + blockIdx.x)) * 4096;
    uint4 v0 = *(const uint4*)&transU[m * 72 + c0];
    uint4 v1 = *(const uint4*)&transU[m * 72 + c0 + 8];
    const int g0 = c0 >> 3;
    *(uint4*)&OT[tb + m * 64 + ((g0 ^ (m & 7)) << 3)]       = v0;
    *(uint4*)&OT[tb + m * 64 + (((g0 + 1) ^ (m & 7)) << 3)] = v1;
  } else {
    float* transF = (float*)smem;  // [64][68]
#pragma unroll
    for (int nf = 0; nf < 2; ++nf) {
      const int c = wc * 32 + nf * 16 + (l & 15);
      const float bias = Wbase[(size_t)K * N + n0 + c];
#pragma unroll
      for (int mf = 0; mf < 2; ++mf)
#pragma unroll
        for (int j = 0; j < 4; ++j) {
          const int m = wr * 32 + mf * 16 + (l >> 4) * 4 + j;
          transF[m * 68 + c] = acc[mf][nf][j] + bias;
        }
    }
    __syncthreads();
    const int m  = t >> 2;
    const int c0 = (t & 3) * 16;
    float* og = Of + ((size_t)m * NE + e) * ND + n0 + c0;
    *(float4*)&og[0]  = *(const float4*)&transF[m * 68 + c0];
    *(float4*)&og[4]  = *(const float4*)&transF[m * 68 + c0 + 4];
    *(float4*)&og[8]  = *(const float4*)&transF[m * 68 + c0 + 8];
    *(float4*)&og[12] = *(const float4*)&transF[m * 68 + c0 + 12];
  }
}

// ---------------------------------------------------------------------------
// Kernel 5: demux/scatter, 16 tokens per block; deterministic fixed-order
// accumulation; zero-fills unpicked tokens.
// ---------------------------------------------------------------------------
__global__ __launch_bounds__(256) void k_scatter(const float* __restrict__ Obuf,
                                                 const float* __restrict__ tval,
                                                 const int* __restrict__ tidx,
                                                 float* __restrict__ out) {
  const int s0 = blockIdx.x * 16;
  const int b  = blockIdx.y;
  const int t  = threadIdx.x;
  const int w  = t >> 6;
  __shared__ unsigned long long masks[16][4];

  const int myIdx = tidx[b * 256 + t];
#pragma unroll
  for (int j = 0; j < 16; ++j) {
    unsigned long long m = __ballot(myIdx == s0 + j);
    if ((t & 63) == 0) masks[j][w] = m;
  }
  __syncthreads();

#pragma unroll
  for (int j = 0; j < 16; ++j) {
    float4 acc = {0.f, 0.f, 0.f, 0.f};
#pragma unroll
    for (int q = 0; q < 4; ++q) {
      unsigned long long mm = masks[j][q];
      while (mm) {
        int bit = __ffsll(mm) - 1;
        mm &= mm - 1;
        int r = q * 64 + bit;
        float v = tval[b * 256 + r];
        const float4 ov = *(const float4*)&Obuf[((size_t)b * NE + (r >> 3)) * ND + t * 4];
        acc.x += v * ov.x; acc.y += v * ov.y; acc.z += v * ov.z; acc.w += v * ov.w;
      }
    }
    *(float4*)&out[((size_t)b * NS + s0 + j) * ND + t * 4] = acc;
  }
}

// ---------------------------------------------------------------------------
extern "C" void kernel_launch(void* const* d_in, const int* in_sizes, int n_in,
                              void* d_out, int out_size, void* d_ws, size_t ws_size,
                              hipStream_t stream) {
  const float* x  = (const float*)d_in[0];
  const float* gw = (const float*)d_in[1];
  const float* w1 = (const float*)d_in[3];
  const float* w2 = (const float*)d_in[4];
  float* out = (float*)d_out;

  char* ws = (char*)d_ws;
  float* logitsT     = (float*)ws;                         // 16,777,216 B
  float* tval        = (float*)(ws + 16777216);            //     65,536 B
  int*   tidx        = (int*)  (ws + 16842752);            //     65,536 B
  unsigned short* A1 = (unsigned short*)(ws + 16908288);   //  4,194,304 B (bf16 tiles)
  unsigned short* Hb = (unsigned short*)(ws + 21102592);   // 16,777,216 B (bf16 tiles)
  float* Obuf        = (float*)(ws + 37879808);            //  8,388,608 B

  k_gate_mfma<<<dim3(NS / 64, NB), 256, 0, stream>>>(x, gw, logitsT);
  k_topk_merge<<<NB * NE, 256, 0, stream>>>(logitsT, x, gw, tval, tidx, A1);
  k_ffn<ND, NH, true ><<<dim3(NH / 64, NE), 256, 0, stream>>>(A1, w1, Hb, nullptr);
  k_ffn<NH, ND, false><<<dim3(ND / 64, NE), 256, 0, stream>>>(Hb, w2, nullptr, Obuf);
  k_scatter<<<dim3(NS / 16, NB), 256, 0, stream>>>(Obuf, tval, tidx, out);
}

// Round 19
// 490.983 us; speedup vs baseline: 1.1011x; 1.0138x over previous
//
#include <hip/hip_runtime.h>
#include <hip/hip_bf16.h>
#include <math.h>

constexpr int NB = 64;     // batch
constexpr int NS = 2048;   // tokens
constexpr int ND = 1024;   // model dim
constexpr int NE = 32;     // experts
constexpr int NH = 4096;   // hidden
constexpr int NK = 8;      // top-k tokens per expert

typedef short bf16x8 __attribute__((ext_vector_type(8)));
typedef float f32x4  __attribute__((ext_vector_type(4)));

__device__ __forceinline__ unsigned short f2bf_rne(float v) {
  unsigned u = __builtin_bit_cast(unsigned, v);
  u += 0x7fffu + ((u >> 16) & 1u);
  return (unsigned short)(u >> 16);
}

__device__ __forceinline__ void gload_lds16(const void* g, void* l) {
  __builtin_amdgcn_global_load_lds(
      (const __attribute__((address_space(1))) unsigned*)g,
      (__attribute__((address_space(3))) unsigned*)l, 16, 0, 0);
}

// order-preserving float->u32 (monotone), and inverse
__device__ __forceinline__ unsigned ford(float f) {
  unsigned u = __builtin_bit_cast(unsigned, f);
  return (u & 0x80000000u) ? ~u : (u | 0x80000000u);
}
__device__ __forceinline__ float finv(unsigned o) {
  unsigned u = (o & 0x80000000u) ? (o & 0x7fffffffu) : ~o;
  return __builtin_bit_cast(float, u);
}

// ---------------------------------------------------------------------------
// Kernel 1: gating GEMM, single-term bf16 MFMA, 64-token tiles, 24KB LDS
// (~6 blocks/CU). T4 pipeline: two register sets, raw s_barrier with
// lgkmcnt-only (no vmcnt drain), x2-unrolled K-loop. (R12/R13 best form.)
// ---------------------------------------------------------------------------
__global__ __launch_bounds__(256) void k_gate_mfma(const float* __restrict__ x,
                                                   const float* __restrict__ gw,
                                                   float* __restrict__ logitsT) {
  const int b  = blockIdx.y;
  const int s0 = blockIdx.x * 64;
  const int t  = threadIdx.x;
  const int l  = t & 63;
  const int w  = t >> 6;

  __shared__ char smem[24576];
  float* trans = (float*)smem;

  f32x4 acc[2] = {};

  const int ar  = t >> 2;
  const int ac4 = (t & 3) * 16;
  const int ge  = t >> 3;
  const int gk  = (t & 7) * 8;

  float xA[4][4], xB[4][4], wA[8], wB[8];

  auto issue = [&](int kt, float (&xreg)[4][4], float (&wreg)[8]) {
    const int k0 = kt * 64;
    const float* xr = &x[((size_t)b * NS + s0 + ar) * ND + k0 + ac4];
#pragma unroll
    for (int j = 0; j < 4; ++j) *(float4*)xreg[j] = *(const float4*)&xr[j * 4];
    *(float4*)&wreg[0] = *(const float4*)&gw[(size_t)ge * ND + k0 + gk];
    *(float4*)&wreg[4] = *(const float4*)&gw[(size_t)ge * ND + k0 + gk + 4];
  };
  auto commit = [&](int dst, float (&xreg)[4][4], float (&wreg)[8]) {
    short* Ah = (short*)(smem + dst * 8192);
    short* Bh = (short*)(smem + 16384 + dst * 4096);
#pragma unroll
    for (int j = 0; j < 4; ++j) {
      unsigned short h[4];
#pragma unroll
      for (int q = 0; q < 4; ++q) h[q] = f2bf_rne(xreg[j][q]);
      const int col = ac4 + j * 4;
      *(ushort4*)&Ah[ar * 64 + (col ^ ((ar & 7) * 8))] = *(const ushort4*)h;
    }
    unsigned short h8[8];
#pragma unroll
    for (int j = 0; j < 8; ++j) h8[j] = f2bf_rne(wreg[j]);
    *(uint4*)&Bh[ge * 64 + (gk ^ ((ge & 7) * 8))] = *(const uint4*)h8;
  };
  auto mfma_phase = [&](int cur) {
    const short* Ah = (const short*)(smem + cur * 8192);
    const short* Bh = (const short*)(smem + 16384 + cur * 4096);
#pragma unroll
    for (int ks = 0; ks < 2; ++ks) {
      const int koff = ks * 32 + (l >> 4) * 8;
      const int rl = w * 16 + (l & 15);
      bf16x8 a = *(const bf16x8*)&Ah[rl * 64 + (koff ^ ((rl & 7) * 8))];
#pragma unroll
      for (int nf = 0; nf < 2; ++nf) {
        const int n = nf * 16 + (l & 15);
        bf16x8 bb = *(const bf16x8*)&Bh[n * 64 + (koff ^ ((n & 7) * 8))];
        acc[nf] = __builtin_amdgcn_mfma_f32_16x16x32_bf16(a, bb, acc[nf], 0, 0, 0);
      }
    }
  };
  auto bar = [&]() {
    asm volatile("s_waitcnt lgkmcnt(0)" ::: "memory");
    __builtin_amdgcn_s_barrier();
    __builtin_amdgcn_sched_barrier(0);
  };

  issue(0, xA, wA);
  issue(1, xB, wB);
  commit(0, xA, wA);
  bar();

  for (int kt = 0; kt < ND / 64; kt += 2) {
    if (kt + 2 < ND / 64) issue(kt + 2, xA, wA);
    commit(1, xB, wB);
    mfma_phase(0);
    bar();
    if (kt + 3 < ND / 64) issue(kt + 3, xB, wB);
    if (kt + 2 < ND / 64) commit(0, xA, wA);
    mfma_phase(1);
    bar();
  }

  // transpose epilogue through LDS for coalesced [e][s] stores
#pragma unroll
  for (int nf = 0; nf < 2; ++nf)
#pragma unroll
    for (int j = 0; j < 4; ++j) {
      const int sl = w * 16 + (l >> 4) * 4 + j;
      const int ec = nf * 16 + (l & 15);
      trans[sl * 33 + ec] = acc[nf][j];
    }
  __syncthreads();
  const int eo = t >> 3, sc = (t & 7) * 8;
#pragma unroll
  for (int q = 0; q < 2; ++q) {
    float4 v;
    v.x = trans[(sc + q * 4 + 0) * 33 + eo];
    v.y = trans[(sc + q * 4 + 1) * 33 + eo];
    v.z = trans[(sc + q * 4 + 2) * 33 + eo];
    v.w = trans[(sc + q * 4 + 3) * 33 + eo];
    *(float4*)&logitsT[((size_t)b * NE + eo) * NS + s0 + sc + q * 4] = v;
  }
}

// ---------------------------------------------------------------------------
// Kernel 2: topk + FUSED merge. Per-wave top-10 (exact per-wave ranking;
// >=3-crossing tolerance for exact-top-8-superset). Merge pool 40 -> approx
// top-12 -> fp64 recheck (3/wave) -> exact top-8 + mux. Outputs identical.
// ---------------------------------------------------------------------------
__global__ __launch_bounds__(256) void k_topk_merge(const float* __restrict__ logitsT,
                                                    const float* __restrict__ x,
                                                    const float* __restrict__ gw,
                                                    float* __restrict__ tval,
                                                    int* __restrict__ tidx,
                                                    unsigned short* __restrict__ A1) {
  const int be = blockIdx.x, b = be >> 5, e = be & 31;
  const float* row = logitsT + (size_t)be * NS;
  const int t = threadIdx.x, w = t >> 6, lane = t & 63;

  __shared__ unsigned long long cvp[40];   // per-wave top-10 packed
  __shared__ int    gci[12];
  __shared__ float  glc[12];
  __shared__ double wsum[4];
  __shared__ float  smax_s;
  __shared__ double ginv;
  __shared__ float  selv[8];
  __shared__ int    seli[8];

  float v[8]; int si[8];
#pragma unroll
  for (int j = 0; j < 8; ++j) {
    const int s = w * 512 + lane + j * 64;
    v[j] = row[s]; si[j] = s;
  }
#pragma unroll
  for (int i = 0; i < 7; ++i)
#pragma unroll
    for (int j = 0; j < 7 - i; ++j) {
      const bool sw = (v[j + 1] > v[j]) || (v[j + 1] == v[j] && si[j + 1] < si[j]);
      const float tv = sw ? v[j + 1] : v[j];
      const int   ti = sw ? si[j + 1] : si[j];
      v[j + 1] = sw ? v[j] : v[j + 1];  si[j + 1] = sw ? si[j] : si[j + 1];
      v[j] = tv;  si[j] = ti;
    }
  const float mxl = v[0];
  double s8 = 1.0;
#pragma unroll
  for (int j = 1; j < 8; ++j) s8 += (double)expf(v[j] - mxl);

  unsigned long long p[8];
#pragma unroll
  for (int j = 0; j < 8; ++j)
    p[j] = ((unsigned long long)ford(v[j]) << 32) | (0xFFFFFFFFu - (unsigned)si[j]);

  // per-wave top-10 by argmax-pop (keys unique; lanes hold complete lists)
  for (int r = 0; r < 10; ++r) {
    unsigned long long m = p[0];
#pragma unroll
    for (int off = 1; off < 64; off <<= 1) {
      const unsigned long long o = __shfl_xor(m, off);
      m = (o > m) ? o : m;
    }
    if (lane == 0) cvp[w * 10 + r] = m;
    if (p[0] == m) {
      p[0]=p[1]; p[1]=p[2]; p[2]=p[3]; p[3]=p[4]; p[4]=p[5]; p[5]=p[6]; p[6]=p[7]; p[7]=0ull;
    }
  }
  __syncthreads();

  // 40 -> 12 merge: parallel rank-select (wave 0, lanes 0..39)
  if (w == 0 && lane < 40) {
    const unsigned long long mine = cvp[lane];
    int rank = 0;
#pragma unroll
    for (int j = 0; j < 40; ++j) rank += (cvp[j] > mine);
    if (rank < 12) {
      gci[rank] = (int)(0xFFFFFFFFu - (unsigned)(mine & 0xFFFFFFFFu));
      if (rank == 0) smax_s = finv((unsigned)(mine >> 32));
    }
  }
  __syncthreads();

  const float mx = smax_s;
  double lsum = s8 * (double)expf(mxl - mx);
#pragma unroll
  for (int off = 32; off; off >>= 1) lsum += __shfl_xor(lsum, off);
  if (lane == 0) wsum[w] = lsum;
  __syncthreads();
  if (t == 0) ginv = 1.0 / (wsum[0] + wsum[1] + wsum[2] + wsum[3]);

  // fp64 recheck: wave w -> candidates 3w..3w+2
  const int kb = lane * 16;
  float gwl[16];
  *(float4*)&gwl[0]  = *(const float4*)&gw[(size_t)e * ND + kb];
  *(float4*)&gwl[4]  = *(const float4*)&gw[(size_t)e * ND + kb + 4];
  *(float4*)&gwl[8]  = *(const float4*)&gw[(size_t)e * ND + kb + 8];
  *(float4*)&gwl[12] = *(const float4*)&gw[(size_t)e * ND + kb + 12];
#pragma unroll
  for (int q = 0; q < 3; ++q) {
    const int c = w * 3 + q;
    const int ciq = gci[c];
    const float* xr = x + ((size_t)b * NS + ciq) * ND + kb;
    float xv[16];
    *(float4*)&xv[0]  = *(const float4*)&xr[0];
    *(float4*)&xv[4]  = *(const float4*)&xr[4];
    *(float4*)&xv[8]  = *(const float4*)&xr[8];
    *(float4*)&xv[12] = *(const float4*)&xr[12];
    double d = 0.0;
#pragma unroll
    for (int j2 = 0; j2 < 16; ++j2) d += (double)xv[j2] * (double)gwl[j2];
#pragma unroll
    for (int off = 32; off; off >>= 1) d += __shfl_xor(d, off);
    if (lane == 0) glc[c] = (float)d;
  }
  __syncthreads();
  if (t < 12) {
    const float mylc = glc[t]; const int myci = gci[t];
    int rank = 0;
#pragma unroll
    for (int c2 = 0; c2 < 12; ++c2) {
      if (c2 == t) continue;
      rank += (glc[c2] > mylc) || (glc[c2] == mylc && gci[c2] < myci);
    }
    if (rank < 8) {
      const float pv = (float)((double)expf(mylc - mx) * ginv);
      tval[be * 8 + rank] = pv;
      tidx[be * 8 + rank] = myci;
      selv[rank] = pv;
      seli[rank] = myci;
    }
  }
  __syncthreads();

  // fused mux/merge (rank order, identical to old k_merge)
  float4 acc4 = {0.f, 0.f, 0.f, 0.f};
#pragma unroll
  for (int k = 0; k < 8; ++k) {
    const float vv = selv[k];
    const int   ss = seli[k];
    const float4 xv4 = *(const float4*)&x[((size_t)b * NS + ss) * ND + t * 4];
    acc4.x += vv * xv4.x; acc4.y += vv * xv4.y;
    acc4.z += vv * xv4.z; acc4.w += vv * xv4.w;
  }
  const int kt = t >> 4;
  const int g  = (t & 15) >> 1;
  const size_t off = ((size_t)(e * 16 + kt)) * 4096 + b * 64 + ((g ^ (b & 7)) << 3) + (t & 1) * 4;
  unsigned short h4[4] = {f2bf_rne(acc4.x), f2bf_rne(acc4.y), f2bf_rne(acc4.z), f2bf_rne(acc4.w)};
  *(ushort4*)&A1[off] = *(const ushort4*)h4;
}

// ---------------------------------------------------------------------------
// Kernels 3/4: per-expert FFN GEMM, single-bf16 MFMA, BN=64, 32KB LDS (R9).
// ---------------------------------------------------------------------------
template <int K, int N, bool GELU>
__global__ __launch_bounds__(256, 4) void k_ffn(const unsigned short* __restrict__ AT,
                                                const float* __restrict__ W,
                                                unsigned short* __restrict__ OT,
                                                float* __restrict__ Of) {
  constexpr int KT = K / 64;
  const int e  = blockIdx.y;
  const int n0 = blockIdx.x * 64;
  const int t  = threadIdx.x, l = t & 63, w = t >> 6;
  const int wr = w >> 1, wc = w & 1;

  __shared__ char smem[32768];

  const float* Wbase = W + (size_t)e * (K + 1) * N;
  f32x4 acc[2][2] = {};

  const int wn  = l;
  const int wk0 = w * 8;
  float wreg[2][8];

  auto issueW = [&](int kt) {
    const float* Wg = Wbase + (size_t)(kt * 64) * N + n0 + wn;
#pragma unroll
    for (int rn = 0; rn < 2; ++rn)
#pragma unroll
      for (int j = 0; j < 8; ++j)
        wreg[rn][j] = Wg[(size_t)(wk0 + rn * 32 + j) * N];
  };
  auto issueA = [&](int kt, int dst) {
    const unsigned short* at = AT + ((size_t)(e * KT + kt)) * 4096;
    char* Ab = smem + dst * 8192;
#pragma unroll
    for (int p = 0; p < 2; ++p)
      gload_lds16(at + p * 2048 + t * 8, Ab + p * 4096 + w * 1024);
  };
  auto commitW = [&](int dst) {
    short* Bb = (short*)(smem + 16384 + dst * 8192);
#pragma unroll
    for (int rn = 0; rn < 2; ++rn) {
      const int kr = (wk0 + rn * 32) >> 3;
      unsigned short s8[8];
#pragma unroll
      for (int j = 0; j < 8; ++j) s8[j] = f2bf_rne(wreg[rn][j]);
      *(uint4*)&Bb[wn * 64 + ((kr ^ (wn & 7)) << 3)] = *(const uint4*)s8;
    }
  };
  auto mfma_phase = [&](int cur) {
    const short* Ab = (const short*)(smem + cur * 8192);
    const short* Bb = (const short*)(smem + 16384 + cur * 8192);
#pragma unroll
    for (int ks = 0; ks < 2; ++ks) {
      const int g8 = ks * 4 + (l >> 4);
      bf16x8 a[2], bb[2];
#pragma unroll
      for (int mf = 0; mf < 2; ++mf) {
        const int m = wr * 32 + mf * 16 + (l & 15);
        a[mf] = *(const bf16x8*)&Ab[m * 64 + ((g8 ^ (m & 7)) << 3)];
      }
#pragma unroll
      for (int nf = 0; nf < 2; ++nf) {
        const int n = wc * 32 + nf * 16 + (l & 15);
        bb[nf] = *(const bf16x8*)&Bb[n * 64 + ((g8 ^ (n & 7)) << 3)];
      }
#pragma unroll
      for (int mf = 0; mf < 2; ++mf)
#pragma unroll
        for (int nf = 0; nf < 2; ++nf)
          acc[mf][nf] = __builtin_amdgcn_mfma_f32_16x16x32_bf16(a[mf], bb[nf], acc[mf][nf], 0, 0, 0);
    }
  };

  issueW(0); issueA(0, 0);
  commitW(0);
  __syncthreads();
  int cur = 0;
  for (int kt = 0; kt < KT; ++kt) {
    const bool more = (kt + 1 < KT);
    if (more) { issueW(kt + 1); issueA(kt + 1, cur ^ 1); }
    mfma_phase(cur);
    if (more) commitW(cur ^ 1);
    __syncthreads();
    cur ^= 1;
  }

  if (GELU) {
    unsigned short* transU = (unsigned short*)smem;  // [64][72]
#pragma unroll
    for (int nf = 0; nf < 2; ++nf) {
      const int c = wc * 32 + nf * 16 + (l & 15);
      const float bias = Wbase[(size_t)K * N + n0 + c];
#pragma unroll
      for (int mf = 0; mf < 2; ++mf)
#pragma unroll
        for (int j = 0; j < 4; ++j) {
          const int m = wr * 32 + mf * 16 + (l >> 4) * 4 + j;
          float vv = acc[mf][nf][j] + bias;
          vv = 0.5f * vv * (1.0f + erff(vv * 0.70710678118654752440f));
          transU[m * 72 + c] = f2bf_rne(vv);
        }
    }
    __syncthreads();
    const int m  = t >> 2;
    const int c0 = (t & 3) * 16;
    const size_t tb = ((size_t)(e * (N / 64) + blockIdx.x)) * 4096;
    uint4 v0 = *(const uint4*)&transU[m * 72 + c0];
    uint4 v1 = *(const uint4*)&transU[m * 72 + c0 + 8];
    const int g0 = c0 >> 3;
    *(uint4*)&OT[tb + m * 64 + ((g0 ^ (m & 7)) << 3)]       = v0;
    *(uint4*)&OT[tb + m * 64 + (((g0 + 1) ^ (m & 7)) << 3)] = v1;
  } else {
    float* transF = (float*)smem;  // [64][68]
#pragma unroll
    for (int nf = 0; nf < 2; ++nf) {
      const int c = wc * 32 + nf * 16 + (l & 15);
      const float bias = Wbase[(size_t)K * N + n0 + c];
#pragma unroll
      for (int mf = 0; mf < 2; ++mf)
#pragma unroll
        for (int j = 0; j < 4; ++j) {
          const int m = wr * 32 + mf * 16 + (l >> 4) * 4 + j;
          transF[m * 68 + c] = acc[mf][nf][j] + bias;
        }
    }
    __syncthreads();
    const int m  = t >> 2;
    const int c0 = (t & 3) * 16;
    float* og = Of + ((size_t)m * NE + e) * ND + n0 + c0;
    *(float4*)&og[0]  = *(const float4*)&transF[m * 68 + c0];
    *(float4*)&og[4]  = *(const float4*)&transF[m * 68 + c0 + 4];
    *(float4*)&og[8]  = *(const float4*)&transF[m * 68 + c0 + 8];
    *(float4*)&og[12] = *(const float4*)&transF[m * 68 + c0 + 12];
  }
}

// ---------------------------------------------------------------------------
// Kernel 5: demux/scatter, 16 tokens per block; deterministic fixed-order
// accumulation; zero-fills unpicked tokens.
// ---------------------------------------------------------------------------
__global__ __launch_bounds__(256) void k_scatter(const float* __restrict__ Obuf,
                                                 const float* __restrict__ tval,
                                                 const int* __restrict__ tidx,
                                                 float* __restrict__ out) {
  const int s0 = blockIdx.x * 16;
  const int b  = blockIdx.y;
  const int t  = threadIdx.x;
  const int w  = t >> 6;
  __shared__ unsigned long long masks[16][4];

  const int myIdx = tidx[b * 256 + t];
#pragma unroll
  for (int j = 0; j < 16; ++j) {
    unsigned long long m = __ballot(myIdx == s0 + j);
    if ((t & 63) == 0) masks[j][w] = m;
  }
  __syncthreads();

#pragma unroll
  for (int j = 0; j < 16; ++j) {
    float4 acc = {0.f, 0.f, 0.f, 0.f};
#pragma unroll
    for (int q = 0; q < 4; ++q) {
      unsigned long long mm = masks[j][q];
      while (mm) {
        int bit = __ffsll(mm) - 1;
        mm &= mm - 1;
        int r = q * 64 + bit;
        float v = tval[b * 256 + r];
        const float4 ov = *(const float4*)&Obuf[((size_t)b * NE + (r >> 3)) * ND + t * 4];
        acc.x += v * ov.x; acc.y += v * ov.y; acc.z += v * ov.z; acc.w += v * ov.w;
      }
    }
    *(float4*)&out[((size_t)b * NS + s0 + j) * ND + t * 4] = acc;
  }
}

// ---------------------------------------------------------------------------
extern "C" void kernel_launch(void* const* d_in, const int* in_sizes, int n_in,
                              void* d_out, int out_size, void* d_ws, size_t ws_size,
                              hipStream_t stream) {
  const float* x  = (const float*)d_in[0];
  const float* gw = (const float*)d_in[1];
  const float* w1 = (const float*)d_in[3];
  const float* w2 = (const float*)d_in[4];
  float* out = (float*)d_out;

  char* ws = (char*)d_ws;
  float* logitsT     = (float*)ws;                         // 16,777,216 B
  float* tval        = (float*)(ws + 16777216);            //     65,536 B
  int*   tidx        = (int*)  (ws + 16842752);            //     65,536 B
  unsigned short* A1 = (unsigned short*)(ws + 16908288);   //  4,194,304 B (bf16 tiles)
  unsigned short* Hb = (unsigned short*)(ws + 21102592);   // 16,777,216 B (bf16 tiles)
  float* Obuf        = (float*)(ws + 37879808);            //  8,388,608 B

  k_gate_mfma<<<dim3(NS / 64, NB), 256, 0, stream>>>(x, gw, logitsT);
  k_topk_merge<<<NB * NE, 256, 0, stream>>>(logitsT, x, gw, tval, tidx, A1);
  k_ffn<ND, NH, true ><<<dim3(NH / 64, NE), 256, 0, stream>>>(A1, w1, Hb, nullptr);
  k_ffn<NH, ND, false><<<dim3(ND / 64, NE), 256, 0, stream>>>(Hb, w2, nullptr, Obuf);
  k_scatter<<<dim3(NS / 16, NB), 256, 0, stream>>>(Obuf, tval, tidx, out);
}